// Round 1
// baseline (4314.300 us; speedup 1.0000x reference)
//
#include <hip/hip_runtime.h>
#include <hip/hip_bf16.h>
#include <cstdint>
#include <cstddef>

// Pipeline: video[2,24,256,256,3] --conv1(7x7,s2)->[.,128,128,64]
//           --conv2(3x3,s2)->[.,64,64,128] --conv3(3x3,s2)->feat[.,32,32,256]
//           bilinear-sample q[2,512,256]; corr+softmax -> pred[2,512,24,2], occl[2,512,24]

__device__ __forceinline__ float bflo(unsigned u) { return __uint_as_float(u << 16); }
__device__ __forceinline__ float bfhi(unsigned u) { return __uint_as_float(u & 0xffff0000u); }

// ---------- conv1: video [48,256,256,3] f32 -> [48,128,128,64] bf16 ----------
// block 256 = 64 channels x 4 ox-quarters; each thread computes 32 ox via rolling window
__global__ __launch_bounds__(256) void k_conv1(const float* __restrict__ video,
                                               const float* __restrict__ w1,
                                               const float* __restrict__ b1,
                                               __hip_bfloat16* __restrict__ out)
{
    __shared__ float lw[7 * 7 * 3 * 64];
    for (int i = threadIdx.x; i < 7 * 7 * 3 * 64; i += 256) lw[i] = w1[i];
    __syncthreads();

    const int c   = threadIdx.x & 63;
    const int q4  = threadIdx.x >> 6;
    const int oy  = blockIdx.x & 127;
    const int bt  = blockIdx.x >> 7;
    const int ox0 = q4 * 32;

    float acc[32];
#pragma unroll
    for (int i = 0; i < 32; ++i) acc[i] = 0.f;

    for (int kh = 0; kh < 7; ++kh) {
        const int iy = oy * 2 - 2 + kh;   // SAME pad: total 5, lo=2
        if ((unsigned)iy >= 256u) continue;
        const float* vrow = video + ((size_t)bt * 256 + iy) * 256 * 3;
#pragma unroll
        for (int ci = 0; ci < 3; ++ci) {
            float wk[7];
#pragma unroll
            for (int kw = 0; kw < 7; ++kw) wk[kw] = lw[((kh * 7 + kw) * 3 + ci) * 64 + c];
            const int ixb = ox0 * 2 - 2;
            float r[7];
#pragma unroll
            for (int j = 0; j < 7; ++j) {
                const int ix = ixb + j;
                r[j] = ((unsigned)ix < 256u) ? vrow[ix * 3 + ci] : 0.f;
            }
#pragma unroll
            for (int i = 0; i < 32; ++i) {
                acc[i] += wk[0]*r[0] + wk[1]*r[1] + wk[2]*r[2] + wk[3]*r[3]
                        + wk[4]*r[4] + wk[5]*r[5] + wk[6]*r[6];
                if (i < 31) {
#pragma unroll
                    for (int j = 0; j < 5; ++j) r[j] = r[j + 2];
                    const int ixa = ixb + 7 + 2 * i;
                    const int ixc = ixb + 8 + 2 * i;
                    r[5] = ((unsigned)ixa < 256u) ? vrow[ixa * 3 + ci] : 0.f;
                    r[6] = ((unsigned)ixc < 256u) ? vrow[ixc * 3 + ci] : 0.f;
                }
            }
        }
    }

    const float bias = b1[c];
    __hip_bfloat16* orow = out + (((size_t)bt * 128 + oy) * 128 + ox0) * 64 + c;
#pragma unroll
    for (int i = 0; i < 32; ++i) {
        float v = fmaxf(acc[i] * (1.f / 255.f) + bias, 0.f);   // x/255 folded out of the conv
        orow[(size_t)i * 64] = __float2bfloat16(v);
    }
}

// ---------- conv2: [48,128,128,64] bf16 -> [48,64,64,128] bf16 ----------
// block 256 = 128 channels x 2 ox-halves; each thread 32 ox; w2 staged per-tap (32KB)
__global__ __launch_bounds__(256) void k_conv2(const __hip_bfloat16* __restrict__ in,
                                               const float* __restrict__ w2,
                                               const float* __restrict__ b2,
                                               __hip_bfloat16* __restrict__ out)
{
    __shared__ float lw[64 * 128];
    const int c    = threadIdx.x & 127;
    const int half = threadIdx.x >> 7;
    const int oy   = blockIdx.x & 63;
    const int bt   = blockIdx.x >> 6;
    const int ox0  = half * 32;

    float acc[32];
#pragma unroll
    for (int i = 0; i < 32; ++i) acc[i] = 0.f;

    for (int kh = 0; kh < 3; ++kh) {
        for (int kw = 0; kw < 3; ++kw) {
            __syncthreads();
            for (int i = threadIdx.x; i < 64 * 128; i += 256)
                lw[i] = w2[(size_t)((kh * 3 + kw) * 64) * 128 + i];
            __syncthreads();
            const int iy = oy * 2 + kh;    // SAME pad: lo=0, hi=1
            if (iy >= 128) continue;       // block-uniform
            const __hip_bfloat16* irow = in + ((size_t)bt * 128 + iy) * 128 * 64;
            for (int c8 = 0; c8 < 8; ++c8) {
                float wv[8];
#pragma unroll
                for (int j = 0; j < 8; ++j) wv[j] = lw[(c8 * 8 + j) * 128 + c];
#pragma unroll
                for (int i = 0; i < 32; ++i) {
                    const int ix = (ox0 + i) * 2 + kw;
                    if (ix < 128) {
                        const uint4 v = *reinterpret_cast<const uint4*>(irow + (size_t)ix * 64 + c8 * 8);
                        acc[i] += bflo(v.x) * wv[0] + bfhi(v.x) * wv[1]
                                + bflo(v.y) * wv[2] + bfhi(v.y) * wv[3]
                                + bflo(v.z) * wv[4] + bfhi(v.z) * wv[5]
                                + bflo(v.w) * wv[6] + bfhi(v.w) * wv[7];
                    }
                }
            }
        }
    }

    const float bias = b2[c];
    __hip_bfloat16* orow = out + (((size_t)bt * 64 + oy) * 64 + ox0) * 128 + c;
#pragma unroll
    for (int i = 0; i < 32; ++i) {
        float v = fmaxf(acc[i] + bias, 0.f);
        orow[(size_t)i * 128] = __float2bfloat16(v);
    }
}

// ---------- conv3: [48,64,64,128] bf16 -> features [48,32,32,256] f32 ----------
// block 256 = 256 channels; each thread owns a full output row (32 ox)
__global__ __launch_bounds__(256) void k_conv3(const __hip_bfloat16* __restrict__ in,
                                               const float* __restrict__ w3,
                                               const float* __restrict__ b3,
                                               float* __restrict__ feat)
{
    __shared__ float lw[32 * 256];
    const int c  = threadIdx.x;
    const int oy = blockIdx.x & 31;
    const int bt = blockIdx.x >> 5;

    float acc[32];
#pragma unroll
    for (int i = 0; i < 32; ++i) acc[i] = 0.f;

    for (int kh = 0; kh < 3; ++kh) {
        for (int kw = 0; kw < 3; ++kw) {
            const int iy = oy * 2 + kh;
            const bool vy = (iy < 64);
            const __hip_bfloat16* irow = in + ((size_t)bt * 64 + iy) * 64 * 128;
            for (int cq = 0; cq < 4; ++cq) {
                __syncthreads();
                for (int i = threadIdx.x; i < 32 * 256; i += 256)
                    lw[i] = w3[((size_t)(kh * 3 + kw) * 128 + cq * 32) * 256 + i];
                __syncthreads();
                if (!vy) continue;          // block-uniform
                for (int c8 = 0; c8 < 4; ++c8) {
                    float wv[8];
#pragma unroll
                    for (int j = 0; j < 8; ++j) wv[j] = lw[(c8 * 8 + j) * 256 + c];
#pragma unroll
                    for (int i = 0; i < 32; ++i) {
                        const int ix = i * 2 + kw;
                        if (ix < 64) {
                            const uint4 v = *reinterpret_cast<const uint4*>(irow + (size_t)ix * 128 + cq * 32 + c8 * 8);
                            acc[i] += bflo(v.x) * wv[0] + bfhi(v.x) * wv[1]
                                    + bflo(v.y) * wv[2] + bfhi(v.y) * wv[3]
                                    + bflo(v.z) * wv[4] + bfhi(v.z) * wv[5]
                                    + bflo(v.w) * wv[6] + bfhi(v.w) * wv[7];
                        }
                    }
                }
            }
        }
    }

    const float bias = b3[c];
    float* orow = feat + (((size_t)bt * 32 + oy) * 32) * 256 + c;
#pragma unroll
    for (int i = 0; i < 32; ++i)
        orow[(size_t)i * 256] = fmaxf(acc[i] + bias, 0.f);
}

// ---------- bilinear query sampling: 1024 blocks (b,n) x 256 threads (c) ----------
__global__ __launch_bounds__(256) void k_sample(const float* __restrict__ qp,
                                                const float* __restrict__ feat,
                                                float* __restrict__ q)
{
    const int bn = blockIdx.x;
    const int b  = bn >> 9;
    const float t3 = qp[bn * 3 + 0];
    const float yv = qp[bn * 3 + 1] * 31.f;
    const float xv = qp[bn * 3 + 2] * 31.f;
    int t = (int)(t3 * 23.f);
    t = min(max(t, 0), 23);
    int y0 = (int)floorf(yv); y0 = min(max(y0, 0), 31);
    const int y1 = min(y0 + 1, 31);
    int x0 = (int)floorf(xv); x0 = min(max(x0, 0), 31);
    const int x1 = min(x0 + 1, 31);
    const float wy1 = yv - (float)y0, wy0 = 1.f - wy1;
    const float wx1 = xv - (float)x0, wx0 = 1.f - wx1;

    const int c = threadIdx.x;
    const float* fb = feat + ((size_t)(b * 24 + t) * 1024) * 256;
    const float f00 = fb[((size_t)(y0 * 32 + x0)) * 256 + c];
    const float f01 = fb[((size_t)(y0 * 32 + x1)) * 256 + c];
    const float f10 = fb[((size_t)(y1 * 32 + x0)) * 256 + c];
    const float f11 = fb[((size_t)(y1 * 32 + x1)) * 256 + c];
    q[(size_t)bn * 256 + c] = (f00 * wx0 + f01 * wx1) * wy0 + (f10 * wx0 + f11 * wx1) * wy1;
}

// ---------- correlation + online softmax + pred/occlusion ----------
// grid = 2*24*8 blocks (b,t,64-query chunk); 256 threads = 64 queries x 4 channel-groups
__global__ __launch_bounds__(256) void k_corr(const float* __restrict__ q,
                                              const float* __restrict__ feat,
                                              float* __restrict__ outp)
{
    __shared__ float xs[32 * 256];
    const int blk = blockIdx.x;
    const int nc  = blk & 7;
    const int t   = (blk >> 3) % 24;
    const int b   = blk / 192;
    const int qi  = threadIdx.x >> 2;
    const int cg  = threadIdx.x & 3;
    const int n   = nc * 64 + qi;

    float qr[64];
    const float* qv = q + ((size_t)(b * 512 + n)) * 256 + cg * 64;
#pragma unroll
    for (int j = 0; j < 16; ++j) {
        const float4 v = reinterpret_cast<const float4*>(qv)[j];
        qr[j * 4 + 0] = v.x; qr[j * 4 + 1] = v.y; qr[j * 4 + 2] = v.z; qr[j * 4 + 3] = v.w;
    }

    float m = -1e30f, s = 0.f, sx = 0.f, sy = 0.f, dmax = -1e30f;
    const float* fimg = feat + (size_t)(b * 24 + t) * 1024 * 256;

    for (int k0 = 0; k0 < 1024; k0 += 32) {
        __syncthreads();
        const float4* src = reinterpret_cast<const float4*>(fimg + (size_t)k0 * 256);
        for (int i = threadIdx.x; i < 2048; i += 256)
            reinterpret_cast<float4*>(xs)[i] = src[i];
        __syncthreads();
        for (int kk = 0; kk < 32; ++kk) {
            const float* xr = xs + kk * 256 + cg * 64;
            float d = 0.f;
#pragma unroll
            for (int j = 0; j < 16; ++j) {
                const float4 v = reinterpret_cast<const float4*>(xr)[j];
                d += v.x * qr[j*4+0] + v.y * qr[j*4+1] + v.z * qr[j*4+2] + v.w * qr[j*4+3];
            }
            d += __shfl_xor(d, 1);
            d += __shfl_xor(d, 2);          // full dot on all 4 lanes of the quad
            dmax = fmaxf(dmax, d);
            const float l  = d * 0.625f;    // (dot/16)*10
            const float nm = fmaxf(m, l);
            const float sc = __expf(m - nm);
            const float e  = __expf(l - nm);
            const int k = k0 + kk;
            s  = s  * sc + e;
            sx = sx * sc + e * (float)(k & 31);
            sy = sy * sc + e * (float)(k >> 5);
            m = nm;
        }
    }

    if (cg == 0) {
        const size_t idx = ((size_t)(b * 512 + n)) * 24 + t;
        const float inv = 1.f / s;
        outp[idx * 2 + 0] = sx * inv * 8.f;          // x * (W/fW)
        outp[idx * 2 + 1] = sy * inv * 8.f;          // y * (H/fH)
        outp[49152 + idx] = 1.f / (1.f + __expf(dmax * 0.0625f));  // sigmoid(-corr_max)
    }
}

extern "C" void kernel_launch(void* const* d_in, const int* in_sizes, int n_in,
                              void* d_out, int out_size, void* d_ws, size_t ws_size,
                              hipStream_t stream)
{
    const float* video = (const float*)d_in[0];
    const float* qp    = (const float*)d_in[1];
    const float* w1    = (const float*)d_in[2];
    const float* b1    = (const float*)d_in[3];
    const float* w2    = (const float*)d_in[4];
    const float* b2    = (const float*)d_in[5];
    const float* w3    = (const float*)d_in[6];
    const float* b3    = (const float*)d_in[7];
    float* out = (float*)d_out;

    char* wsb = (char*)d_ws;
    __hip_bfloat16* c1o = (__hip_bfloat16*)(wsb);                    // 100,663,296 B
    __hip_bfloat16* c2o = (__hip_bfloat16*)(wsb + 100663296ull);     //  50,331,648 B
    float* feat = (float*)(wsb + 150994944ull);                      //  50,331,648 B
    float* qv   = (float*)(wsb + 201326592ull);                      //   1,048,576 B

    hipLaunchKernelGGL(k_conv1,  dim3(48 * 128), dim3(256), 0, stream, video, w1, b1, c1o);
    hipLaunchKernelGGL(k_conv2,  dim3(48 * 64),  dim3(256), 0, stream, c1o, w2, b2, c2o);
    hipLaunchKernelGGL(k_conv3,  dim3(48 * 32),  dim3(256), 0, stream, c2o, w3, b3, feat);
    hipLaunchKernelGGL(k_sample, dim3(1024),     dim3(256), 0, stream, qp, feat, qv);
    hipLaunchKernelGGL(k_corr,   dim3(384),      dim3(256), 0, stream, qv, feat, out);
}

// Round 2
// 1223.628 us; speedup vs baseline: 3.5258x; 3.5258x over previous
//
#include <hip/hip_runtime.h>
#include <hip/hip_bf16.h>
#include <cstdint>
#include <cstddef>

// Pipeline: video[2,24,256,256,3] --conv1(7x7,s2,VALU)->[48,128,128,64]bf16
//           --conv2(3x3,s2,MFMA)->[48,64,64,128]bf16 --conv3(3x3,s2,MFMA)->feat[48,32,32,256]bf16
//           bilinear-sample q[1024,256]bf16; corr(MFMA)+online softmax -> pred/occl f32
//
// MFMA 16x16x32 bf16 layouts (verified, cdna_hip_programming §3):
//   A: lane holds row=l&15,   k=(l>>4)*8+j  (bf16x8, j contiguous)
//   B: lane holds col=l&15,   k=(l>>4)*8+j
//   C: lane holds col=l&15, row=(l>>4)*4+reg (f32x4)

typedef __attribute__((ext_vector_type(8))) short bf16x8;
typedef __attribute__((ext_vector_type(4))) float f32x4;

__device__ __forceinline__ bf16x8 zero8() { bf16x8 z = {0,0,0,0,0,0,0,0}; return z; }

// ---------- conv1 (unchanged, VALU): video f32 -> [48,128,128,64] bf16 ----------
__global__ __launch_bounds__(256) void k_conv1(const float* __restrict__ video,
                                               const float* __restrict__ w1,
                                               const float* __restrict__ b1,
                                               __hip_bfloat16* __restrict__ out)
{
    __shared__ float lw[7 * 7 * 3 * 64];
    for (int i = threadIdx.x; i < 7 * 7 * 3 * 64; i += 256) lw[i] = w1[i];
    __syncthreads();

    const int c   = threadIdx.x & 63;
    const int q4  = threadIdx.x >> 6;
    const int oy  = blockIdx.x & 127;
    const int bt  = blockIdx.x >> 7;
    const int ox0 = q4 * 32;

    float acc[32];
#pragma unroll
    for (int i = 0; i < 32; ++i) acc[i] = 0.f;

    for (int kh = 0; kh < 7; ++kh) {
        const int iy = oy * 2 - 2 + kh;   // SAME pad: total 5, lo=2
        if ((unsigned)iy >= 256u) continue;
        const float* vrow = video + ((size_t)bt * 256 + iy) * 256 * 3;
#pragma unroll
        for (int ci = 0; ci < 3; ++ci) {
            float wk[7];
#pragma unroll
            for (int kw = 0; kw < 7; ++kw) wk[kw] = lw[((kh * 7 + kw) * 3 + ci) * 64 + c];
            const int ixb = ox0 * 2 - 2;
            float r[7];
#pragma unroll
            for (int j = 0; j < 7; ++j) {
                const int ix = ixb + j;
                r[j] = ((unsigned)ix < 256u) ? vrow[ix * 3 + ci] : 0.f;
            }
#pragma unroll
            for (int i = 0; i < 32; ++i) {
                acc[i] += wk[0]*r[0] + wk[1]*r[1] + wk[2]*r[2] + wk[3]*r[3]
                        + wk[4]*r[4] + wk[5]*r[5] + wk[6]*r[6];
                if (i < 31) {
#pragma unroll
                    for (int j = 0; j < 5; ++j) r[j] = r[j + 2];
                    const int ixa = ixb + 7 + 2 * i;
                    const int ixc = ixb + 8 + 2 * i;
                    r[5] = ((unsigned)ixa < 256u) ? vrow[ixa * 3 + ci] : 0.f;
                    r[6] = ((unsigned)ixc < 256u) ? vrow[ixc * 3 + ci] : 0.f;
                }
            }
        }
    }

    const float bias = b1[c];
    __hip_bfloat16* orow = out + (((size_t)bt * 128 + oy) * 128 + ox0) * 64 + c;
#pragma unroll
    for (int i = 0; i < 32; ++i) {
        float v = fmaxf(acc[i] * (1.f / 255.f) + bias, 0.f);
        orow[(size_t)i * 64] = __float2bfloat16(v);
    }
}

// ---------- weight repack: f32 -> bf16 B-fragment order ----------
// Wp2[tap][ks(2)][ntile(8)][lane(64)][j(8)]  <- w2[kh,kw,ci,n], ci=ks*32+(l>>4)*8+j, n=nt*16+(l&15)
__global__ __launch_bounds__(256) void k_repack2(const float* __restrict__ w2,
                                                 __hip_bfloat16* __restrict__ wp)
{
    const int e = blockIdx.x * 256 + threadIdx.x;      // 73728 elems
    const int j = e & 7, lane = (e >> 3) & 63, nt = (e >> 9) & 7, ks = (e >> 12) & 1, tap = e >> 13;
    const int ci = ks * 32 + ((lane >> 4) << 3) + j;
    const int n  = nt * 16 + (lane & 15);
    wp[e] = __float2bfloat16(w2[(size_t)(tap * 64 + ci) * 128 + n]);
}

// Wp3[tap][ks(4)][ntile(16)][lane(64)][j(8)]
__global__ __launch_bounds__(256) void k_repack3(const float* __restrict__ w3,
                                                 __hip_bfloat16* __restrict__ wp)
{
    const int e = blockIdx.x * 256 + threadIdx.x;      // 294912 elems
    const int j = e & 7, lane = (e >> 3) & 63, nt = (e >> 9) & 15, ks = (e >> 13) & 3, tap = e >> 15;
    const int ci = ks * 32 + ((lane >> 4) << 3) + j;
    const int n  = nt * 16 + (lane & 15);
    wp[e] = __float2bfloat16(w3[(size_t)(tap * 128 + ci) * 256 + n]);
}

// ---------- conv2 MFMA: [48,128,128,64]bf16 -> [48,64,64,128]bf16 ----------
// block = (bt, oy); 4 waves, wave w owns pixels ox in [w*16, w*16+16), N=128 (8 ntiles)
__global__ __launch_bounds__(256) void k_conv2m(const __hip_bfloat16* __restrict__ in,
                                                const __hip_bfloat16* __restrict__ wp,
                                                const float* __restrict__ b2,
                                                __hip_bfloat16* __restrict__ out)
{
    const int oy = blockIdx.x & 63;
    const int bt = blockIdx.x >> 6;
    const int w  = threadIdx.x >> 6;
    const int l  = threadIdx.x & 63;
    const int li = l & 15, lh = l >> 4;

    f32x4 acc[8];
#pragma unroll
    for (int i = 0; i < 8; ++i) acc[i] = (f32x4){0.f, 0.f, 0.f, 0.f};

    const int oxA = w * 16 + li;
    const short* inS = (const short*)in;
    const short* wS  = (const short*)wp;

    for (int kh = 0; kh < 3; ++kh) {
        const int iy = oy * 2 + kh;           // SAME: lo=0, hi=1
        if (iy >= 128) continue;              // block-uniform
#pragma unroll
        for (int kw = 0; kw < 3; ++kw) {
            const int ix  = oxA * 2 + kw;
            const bool vld = (ix < 128);
            const size_t abase = (((size_t)bt * 128 + iy) * 128 + (vld ? ix : 0)) * 64 + lh * 8;
            const int tap = kh * 3 + kw;
#pragma unroll
            for (int ks = 0; ks < 2; ++ks) {
                bf16x8 a = *reinterpret_cast<const bf16x8*>(inS + abase + ks * 32);
                if (!vld) a = zero8();
                const short* wbase = wS + ((size_t)(tap * 2 + ks) * 8 * 64 + l) * 8;
#pragma unroll
                for (int nt = 0; nt < 8; ++nt) {
                    bf16x8 bv = *reinterpret_cast<const bf16x8*>(wbase + nt * 512);
                    acc[nt] = __builtin_amdgcn_mfma_f32_16x16x32_bf16(a, bv, acc[nt], 0, 0, 0);
                }
            }
        }
    }

    const int oxC = w * 16 + lh * 4;
    __hip_bfloat16* op = out + (((size_t)bt * 64 + oy) * 64) * 128;
#pragma unroll
    for (int nt = 0; nt < 8; ++nt) {
        const int n = nt * 16 + li;
        const float bias = b2[n];
#pragma unroll
        for (int r = 0; r < 4; ++r) {
            const float v = fmaxf(acc[nt][r] + bias, 0.f);
            op[(size_t)(oxC + r) * 128 + n] = __float2bfloat16(v);
        }
    }
}

// ---------- conv3 MFMA: [48,64,64,128]bf16 -> feat [48,32,32,256]bf16 ----------
// block = (bt, oy); wave w: mtile=w&1 (16 px), nhalf=w>>1 (128 ch = 8 ntiles)
__global__ __launch_bounds__(256) void k_conv3m(const __hip_bfloat16* __restrict__ in,
                                                const __hip_bfloat16* __restrict__ wp,
                                                const float* __restrict__ b3,
                                                __hip_bfloat16* __restrict__ feat)
{
    const int oy = blockIdx.x & 31;
    const int bt = blockIdx.x >> 5;
    const int w  = threadIdx.x >> 6;
    const int l  = threadIdx.x & 63;
    const int li = l & 15, lh = l >> 4;
    const int mt = w & 1, nh = w >> 1;

    f32x4 acc[8];
#pragma unroll
    for (int i = 0; i < 8; ++i) acc[i] = (f32x4){0.f, 0.f, 0.f, 0.f};

    const int oxA = mt * 16 + li;
    const short* inS = (const short*)in;
    const short* wS  = (const short*)wp;

    for (int kh = 0; kh < 3; ++kh) {
        const int iy = oy * 2 + kh;
        if (iy >= 64) continue;               // block-uniform
#pragma unroll
        for (int kw = 0; kw < 3; ++kw) {
            const int ix  = oxA * 2 + kw;
            const bool vld = (ix < 64);
            const size_t abase = (((size_t)bt * 64 + iy) * 64 + (vld ? ix : 0)) * 128 + lh * 8;
            const int tap = kh * 3 + kw;
#pragma unroll
            for (int ks = 0; ks < 4; ++ks) {
                bf16x8 a = *reinterpret_cast<const bf16x8*>(inS + abase + ks * 32);
                if (!vld) a = zero8();
                const short* wbase = wS + ((size_t)((tap * 4 + ks) * 16 + nh * 8) * 64 + l) * 8;
#pragma unroll
                for (int nt = 0; nt < 8; ++nt) {
                    bf16x8 bv = *reinterpret_cast<const bf16x8*>(wbase + nt * 512);
                    acc[nt] = __builtin_amdgcn_mfma_f32_16x16x32_bf16(a, bv, acc[nt], 0, 0, 0);
                }
            }
        }
    }

    const int oxC = mt * 16 + lh * 4;
    __hip_bfloat16* op = feat + (((size_t)bt * 32 + oy) * 32) * 256;
#pragma unroll
    for (int nt = 0; nt < 8; ++nt) {
        const int n = nh * 128 + nt * 16 + li;
        const float bias = b3[n];
#pragma unroll
        for (int r = 0; r < 4; ++r) {
            const float v = fmaxf(acc[nt][r] + bias, 0.f);
            op[(size_t)(oxC + r) * 256 + n] = __float2bfloat16(v);
        }
    }
}

// ---------- bilinear query sampling -> q bf16 [1024,256] ----------
__global__ __launch_bounds__(256) void k_sample(const float* __restrict__ qp,
                                                const __hip_bfloat16* __restrict__ feat,
                                                __hip_bfloat16* __restrict__ q)
{
    const int bn = blockIdx.x;
    const int b  = bn >> 9;
    const float t3 = qp[bn * 3 + 0];
    const float yv = qp[bn * 3 + 1] * 31.f;
    const float xv = qp[bn * 3 + 2] * 31.f;
    int t = (int)(t3 * 23.f);
    t = min(max(t, 0), 23);
    int y0 = (int)floorf(yv); y0 = min(max(y0, 0), 31);
    const int y1 = min(y0 + 1, 31);
    int x0 = (int)floorf(xv); x0 = min(max(x0, 0), 31);
    const int x1 = min(x0 + 1, 31);
    const float wy1 = yv - (float)y0, wy0 = 1.f - wy1;
    const float wx1 = xv - (float)x0, wx0 = 1.f - wx1;

    const int c = threadIdx.x;
    const __hip_bfloat16* fb = feat + ((size_t)(b * 24 + t) * 1024) * 256;
    const float f00 = __bfloat162float(fb[(size_t)(y0 * 32 + x0) * 256 + c]);
    const float f01 = __bfloat162float(fb[(size_t)(y0 * 32 + x1) * 256 + c]);
    const float f10 = __bfloat162float(fb[(size_t)(y1 * 32 + x0) * 256 + c]);
    const float f11 = __bfloat162float(fb[(size_t)(y1 * 32 + x1) * 256 + c]);
    const float v = (f00 * wx0 + f01 * wx1) * wy0 + (f10 * wx0 + f11 * wx1) * wy1;
    q[(size_t)bn * 256 + c] = __float2bfloat16(v);
}

// ---------- correlation MFMA + online softmax ----------
// grid = 2*24*8 (b, t, 64-query chunk); 4 waves, wave owns 16 queries; N=1024 in chunks of 64
__global__ __launch_bounds__(256) void k_corrm(const __hip_bfloat16* __restrict__ qb,
                                               const __hip_bfloat16* __restrict__ featb,
                                               float* __restrict__ outp)
{
    const int blk = blockIdx.x;
    const int nc  = blk & 7;
    const int t   = (blk >> 3) % 24;
    const int bq  = blk / 192;
    const int w   = threadIdx.x >> 6;
    const int l   = threadIdx.x & 63;
    const int li  = l & 15, lh = l >> 4;

    const short* qS = (const short*)qb;
    const short* fS = (const short*)featb + (size_t)(bq * 24 + t) * 1024 * 256;

    // preload all A fragments (16 queries x K=256)
    const int qrowA = nc * 64 + w * 16 + li;
    bf16x8 aq[8];
#pragma unroll
    for (int ks = 0; ks < 8; ++ks)
        aq[ks] = *reinterpret_cast<const bf16x8*>(qS + ((size_t)(bq * 512 + qrowA)) * 256 + ks * 32 + lh * 8);

    float m[4], s[4], sx[4], sy[4], dmx[4];
#pragma unroll
    for (int r = 0; r < 4; ++r) { m[r] = -1e30f; s[r] = 0.f; sx[r] = 0.f; sy[r] = 0.f; dmx[r] = -1e30f; }

    for (int p0 = 0; p0 < 1024; p0 += 64) {
        f32x4 acc[4];
#pragma unroll
        for (int i = 0; i < 4; ++i) acc[i] = (f32x4){0.f, 0.f, 0.f, 0.f};

#pragma unroll
        for (int pt = 0; pt < 4; ++pt) {
            const short* bb = fS + (size_t)(p0 + pt * 16 + li) * 256 + lh * 8;
#pragma unroll
            for (int ks = 0; ks < 8; ++ks) {
                bf16x8 bv = *reinterpret_cast<const bf16x8*>(bb + ks * 32);
                acc[pt] = __builtin_amdgcn_mfma_f32_16x16x32_bf16(aq[ks], bv, acc[pt], 0, 0, 0);
            }
        }

        float px[4], py[4];
#pragma unroll
        for (int pt = 0; pt < 4; ++pt) {
            px[pt] = (float)((pt * 16 + li) & 31);
            py[pt] = (float)((p0 >> 5) + (pt >> 1));
        }

#pragma unroll
        for (int r = 0; r < 4; ++r) {
            const float v0 = acc[0][r], v1 = acc[1][r], v2 = acc[2][r], v3 = acc[3][r];
            float mx = fmaxf(fmaxf(v0, v1), fmaxf(v2, v3));
            mx = fmaxf(mx, __shfl_xor(mx, 1));
            mx = fmaxf(mx, __shfl_xor(mx, 2));
            mx = fmaxf(mx, __shfl_xor(mx, 4));
            mx = fmaxf(mx, __shfl_xor(mx, 8));   // row max over this 64-pos chunk (group-uniform)
            dmx[r] = fmaxf(dmx[r], mx);
            const float mn = fmaxf(m[r], mx * 0.625f);        // logit = dot * (10/16)
            const float sc = __expf(m[r] - mn);
            const float e0 = __expf(v0 * 0.625f - mn);
            const float e1 = __expf(v1 * 0.625f - mn);
            const float e2 = __expf(v2 * 0.625f - mn);
            const float e3 = __expf(v3 * 0.625f - mn);
            s[r]  = s[r]  * sc + (e0 + e1 + e2 + e3);
            sx[r] = sx[r] * sc + (e0 * px[0] + e1 * px[1] + e2 * px[2] + e3 * px[3]);
            sy[r] = sy[r] * sc + (e0 * py[0] + e1 * py[1] + e2 * py[2] + e3 * py[3]);
            m[r] = mn;
        }
    }

    // reduce partial sums across the 16-lane group
#pragma unroll
    for (int r = 0; r < 4; ++r) {
#pragma unroll
        for (int off = 1; off < 16; off <<= 1) {
            s[r]  += __shfl_xor(s[r],  off);
            sx[r] += __shfl_xor(sx[r], off);
            sy[r] += __shfl_xor(sy[r], off);
        }
    }

    if (li == 0) {
#pragma unroll
        for (int r = 0; r < 4; ++r) {
            const int n = nc * 64 + w * 16 + lh * 4 + r;
            const size_t idx = ((size_t)(bq * 512 + n)) * 24 + t;
            const float inv = 8.f / s[r];                         // * (W/fW) = 8
            outp[idx * 2 + 0] = sx[r] * inv;
            outp[idx * 2 + 1] = sy[r] * inv;
            outp[49152 + idx] = 1.f / (1.f + __expf(dmx[r] * 0.0625f));  // sigmoid(-dot/16)
        }
    }
}

extern "C" void kernel_launch(void* const* d_in, const int* in_sizes, int n_in,
                              void* d_out, int out_size, void* d_ws, size_t ws_size,
                              hipStream_t stream)
{
    const float* video = (const float*)d_in[0];
    const float* qp    = (const float*)d_in[1];
    const float* w1    = (const float*)d_in[2];
    const float* b1    = (const float*)d_in[3];
    const float* w2    = (const float*)d_in[4];
    const float* b2    = (const float*)d_in[5];
    const float* w3    = (const float*)d_in[6];
    const float* b3    = (const float*)d_in[7];
    float* out = (float*)d_out;

    char* wsb = (char*)d_ws;
    __hip_bfloat16* c1o   = (__hip_bfloat16*)(wsb);                    // 100,663,296 B
    __hip_bfloat16* c2o   = (__hip_bfloat16*)(wsb + 100663296ull);     //  50,331,648 B
    __hip_bfloat16* featb = (__hip_bfloat16*)(wsb + 150994944ull);     //  25,165,824 B
    __hip_bfloat16* qbuf  = (__hip_bfloat16*)(wsb + 176160768ull);     //     524,288 B
    __hip_bfloat16* w2p   = (__hip_bfloat16*)(wsb + 176685056ull);     //     147,456 B
    __hip_bfloat16* w3p   = (__hip_bfloat16*)(wsb + 176832512ull);     //     589,824 B

    hipLaunchKernelGGL(k_repack2, dim3(288),      dim3(256), 0, stream, w2, w2p);
    hipLaunchKernelGGL(k_repack3, dim3(1152),     dim3(256), 0, stream, w3, w3p);
    hipLaunchKernelGGL(k_conv1,   dim3(48 * 128), dim3(256), 0, stream, video, w1, b1, c1o);
    hipLaunchKernelGGL(k_conv2m,  dim3(48 * 64),  dim3(256), 0, stream, c1o, w2p, b2, c2o);
    hipLaunchKernelGGL(k_conv3m,  dim3(48 * 32),  dim3(256), 0, stream, c2o, w3p, b3, featb);
    hipLaunchKernelGGL(k_sample,  dim3(1024),     dim3(256), 0, stream, qp, featb, qbuf);
    hipLaunchKernelGGL(k_corrm,   dim3(384),      dim3(256), 0, stream, qbuf, featb, out);
}

// Round 3
// 439.097 us; speedup vs baseline: 9.8254x; 2.7867x over previous
//
#include <hip/hip_runtime.h>
#include <hip/hip_bf16.h>
#include <cstdint>
#include <cstddef>

// Pipeline (all convs on MFMA now):
//   k_pad1: video[2,24,256,256,3]f32 -> pv[48,256,264*4]bf16 (x-pad +-2, ci padded 3->4)
//   k_conv1m: pv --7x(16x16x32 MFMA)--> [48,128,128,64]bf16
//   k_conv2m: --> [48,64,64,128]bf16 ; k_conv3m: --> feat[48,32,32,256]bf16
//   k_sample: bilinear q[1024,256]bf16 ; k_corrm: MFMA corr + online softmax -> pred/occl f32
//
// MFMA 16x16x32 bf16 layouts (verified):
//   A: lane l holds row=l&15,   k=(l>>4)*8+j  (bf16x8 contiguous)
//   B: lane l holds col=l&15,   k=(l>>4)*8+j
//   C: lane l holds col=l&15, row=(l>>4)*4+reg (f32x4)

typedef __attribute__((ext_vector_type(8))) short bf16x8;
typedef __attribute__((ext_vector_type(4))) float f32x4;

__device__ __forceinline__ bf16x8 zero8() { bf16x8 z = {0,0,0,0,0,0,0,0}; return z; }
__device__ __forceinline__ unsigned short bfr(float f) {
    return (unsigned short)(__bfloat16_as_ushort(__float2bfloat16(f)));
}

// ---------- pad+cast video: [48,256,256,3]f32 -> [48,256,1056]bf16 ----------
// padded row: px 0..263 (px = ix+2), 4 ch each; px 0,1 and 258..263 are zero
__global__ __launch_bounds__(256) void k_pad1(const float* __restrict__ video,
                                              __hip_bfloat16* __restrict__ pv)
{
    const int iy = blockIdx.x & 255;
    const int bt = blockIdx.x >> 8;
    const int ix = threadIdx.x;
    const float* src = video + ((size_t)(bt * 256 + iy) * 256 + ix) * 3;
    unsigned* dst = (unsigned*)(pv + (size_t)(bt * 256 + iy) * 1056);

    const float v0 = src[0], v1 = src[1], v2 = src[2];
    const unsigned lo = (unsigned)bfr(v0) | ((unsigned)bfr(v1) << 16);
    const unsigned hi = (unsigned)bfr(v2);
    dst[(2 + ix) * 2 + 0] = lo;
    dst[(2 + ix) * 2 + 1] = hi;
    if (ix < 2)   { dst[ix * 2] = 0u; dst[ix * 2 + 1] = 0u; }           // front pad px 0,1
    if (ix >= 250){ dst[(ix + 8) * 2] = 0u; dst[(ix + 8) * 2 + 1] = 0u; } // back pad px 258..263
}

// ---------- w1 repack: [7,7,3,64]f32 -> wp1[kh(7)][nt(4)][lane(64)][j(8)] bf16 ----------
// k = (lane>>4)*8+j in [0,32); kw=k>>2, ci=k&3 (ci==3 or kw==7 -> 0); n = nt*16+(lane&15)
__global__ __launch_bounds__(256) void k_repack1(const float* __restrict__ w1,
                                                 __hip_bfloat16* __restrict__ wp)
{
    const int e = blockIdx.x * 256 + threadIdx.x;      // 14336 elems
    if (e >= 7 * 4 * 64 * 8) return;
    const int j = e & 7, lane = (e >> 3) & 63, nt = (e >> 9) & 3, kh = e >> 11;
    const int k = ((lane >> 4) << 3) + j;
    const int kw = k >> 2, ci = k & 3;
    const int n = nt * 16 + (lane & 15);
    float v = (ci < 3 && kw < 7) ? w1[(size_t)((kh * 7 + kw) * 3 + ci) * 64 + n] : 0.f;
    wp[e] = __float2bfloat16(v);
}

// ---------- conv1 MFMA: pv -> [48,128,128,64]bf16 ----------
// block=(bt,oy), 4 waves; wave w owns pixels [w*32, w*32+32) (2 mtiles), all 64 ch (4 ntiles)
__global__ __launch_bounds__(256) void k_conv1m(const __hip_bfloat16* __restrict__ pv,
                                                const __hip_bfloat16* __restrict__ wp,
                                                const float* __restrict__ b1,
                                                __hip_bfloat16* __restrict__ out)
{
    const int oy = blockIdx.x & 127;
    const int bt = blockIdx.x >> 7;
    const int w  = threadIdx.x >> 6;
    const int l  = threadIdx.x & 63;
    const int li = l & 15, lh = l >> 4;

    f32x4 acc[2][4];
#pragma unroll
    for (int m = 0; m < 2; ++m)
#pragma unroll
        for (int n = 0; n < 4; ++n) acc[m][n] = (f32x4){0.f, 0.f, 0.f, 0.f};

    const short* pvS = (const short*)pv;
    const short* wS  = (const short*)wp;

#pragma unroll
    for (int kh = 0; kh < 7; ++kh) {
        const int iy = oy * 2 - 2 + kh;       // SAME pad: lo=2
        if ((unsigned)iy >= 256u) continue;   // block-uniform
        const short* row = pvS + (size_t)(bt * 256 + iy) * 1056;
        bf16x8 bw[4];
#pragma unroll
        for (int nt = 0; nt < 4; ++nt)
            bw[nt] = *reinterpret_cast<const bf16x8*>(wS + ((size_t)(kh * 4 + nt) * 64 + l) * 8);
#pragma unroll
        for (int mt = 0; mt < 2; ++mt) {
            const int ox = w * 32 + mt * 16 + li;
            bf16x8 a = *reinterpret_cast<const bf16x8*>(row + 8 * (ox + lh));
#pragma unroll
            for (int nt = 0; nt < 4; ++nt)
                acc[mt][nt] = __builtin_amdgcn_mfma_f32_16x16x32_bf16(a, bw[nt], acc[mt][nt], 0, 0, 0);
        }
    }

    __hip_bfloat16* op = out + ((size_t)(bt * 128 + oy) * 128) * 64;
#pragma unroll
    for (int mt = 0; mt < 2; ++mt) {
        const int px0 = w * 32 + mt * 16 + lh * 4;
#pragma unroll
        for (int nt = 0; nt < 4; ++nt) {
            const int n = nt * 16 + li;
            const float bias = b1[n];
#pragma unroll
            for (int r = 0; r < 4; ++r) {
                const float v = fmaxf(acc[mt][nt][r] * (1.f / 255.f) + bias, 0.f);
                op[(size_t)(px0 + r) * 64 + n] = __float2bfloat16(v);
            }
        }
    }
}

// ---------- w2 repack: Wp2[tap][ks(2)][ntile(8)][lane(64)][j(8)] ----------
__global__ __launch_bounds__(256) void k_repack2(const float* __restrict__ w2,
                                                 __hip_bfloat16* __restrict__ wp)
{
    const int e = blockIdx.x * 256 + threadIdx.x;      // 73728 elems
    const int j = e & 7, lane = (e >> 3) & 63, nt = (e >> 9) & 7, ks = (e >> 12) & 1, tap = e >> 13;
    const int ci = ks * 32 + ((lane >> 4) << 3) + j;
    const int n  = nt * 16 + (lane & 15);
    wp[e] = __float2bfloat16(w2[(size_t)(tap * 64 + ci) * 128 + n]);
}

// ---------- w3 repack: Wp3[tap][ks(4)][ntile(16)][lane(64)][j(8)] ----------
__global__ __launch_bounds__(256) void k_repack3(const float* __restrict__ w3,
                                                 __hip_bfloat16* __restrict__ wp)
{
    const int e = blockIdx.x * 256 + threadIdx.x;      // 294912 elems
    const int j = e & 7, lane = (e >> 3) & 63, nt = (e >> 9) & 15, ks = (e >> 13) & 3, tap = e >> 15;
    const int ci = ks * 32 + ((lane >> 4) << 3) + j;
    const int n  = nt * 16 + (lane & 15);
    wp[e] = __float2bfloat16(w3[(size_t)(tap * 128 + ci) * 256 + n]);
}

// ---------- conv2 MFMA: [48,128,128,64]bf16 -> [48,64,64,128]bf16 ----------
__global__ __launch_bounds__(256) void k_conv2m(const __hip_bfloat16* __restrict__ in,
                                                const __hip_bfloat16* __restrict__ wp,
                                                const float* __restrict__ b2,
                                                __hip_bfloat16* __restrict__ out)
{
    const int oy = blockIdx.x & 63;
    const int bt = blockIdx.x >> 6;
    const int w  = threadIdx.x >> 6;
    const int l  = threadIdx.x & 63;
    const int li = l & 15, lh = l >> 4;

    f32x4 acc[8];
#pragma unroll
    for (int i = 0; i < 8; ++i) acc[i] = (f32x4){0.f, 0.f, 0.f, 0.f};

    const int oxA = w * 16 + li;
    const short* inS = (const short*)in;
    const short* wS  = (const short*)wp;

    for (int kh = 0; kh < 3; ++kh) {
        const int iy = oy * 2 + kh;           // SAME: lo=0, hi=1
        if (iy >= 128) continue;              // block-uniform
#pragma unroll
        for (int kw = 0; kw < 3; ++kw) {
            const int ix  = oxA * 2 + kw;
            const bool vld = (ix < 128);
            const size_t abase = (((size_t)bt * 128 + iy) * 128 + (vld ? ix : 0)) * 64 + lh * 8;
            const int tap = kh * 3 + kw;
#pragma unroll
            for (int ks = 0; ks < 2; ++ks) {
                bf16x8 a = *reinterpret_cast<const bf16x8*>(inS + abase + ks * 32);
                if (!vld) a = zero8();
                const short* wbase = wS + ((size_t)(tap * 2 + ks) * 8 * 64 + l) * 8;
#pragma unroll
                for (int nt = 0; nt < 8; ++nt) {
                    bf16x8 bv = *reinterpret_cast<const bf16x8*>(wbase + nt * 512);
                    acc[nt] = __builtin_amdgcn_mfma_f32_16x16x32_bf16(a, bv, acc[nt], 0, 0, 0);
                }
            }
        }
    }

    const int oxC = w * 16 + lh * 4;
    __hip_bfloat16* op = out + (((size_t)bt * 64 + oy) * 64) * 128;
#pragma unroll
    for (int nt = 0; nt < 8; ++nt) {
        const int n = nt * 16 + li;
        const float bias = b2[n];
#pragma unroll
        for (int r = 0; r < 4; ++r) {
            const float v = fmaxf(acc[nt][r] + bias, 0.f);
            op[(size_t)(oxC + r) * 128 + n] = __float2bfloat16(v);
        }
    }
}

// ---------- conv3 MFMA: [48,64,64,128]bf16 -> feat [48,32,32,256]bf16 ----------
__global__ __launch_bounds__(256) void k_conv3m(const __hip_bfloat16* __restrict__ in,
                                                const __hip_bfloat16* __restrict__ wp,
                                                const float* __restrict__ b3,
                                                __hip_bfloat16* __restrict__ feat)
{
    const int oy = blockIdx.x & 31;
    const int bt = blockIdx.x >> 5;
    const int w  = threadIdx.x >> 6;
    const int l  = threadIdx.x & 63;
    const int li = l & 15, lh = l >> 4;
    const int mt = w & 1, nh = w >> 1;

    f32x4 acc[8];
#pragma unroll
    for (int i = 0; i < 8; ++i) acc[i] = (f32x4){0.f, 0.f, 0.f, 0.f};

    const int oxA = mt * 16 + li;
    const short* inS = (const short*)in;
    const short* wS  = (const short*)wp;

    for (int kh = 0; kh < 3; ++kh) {
        const int iy = oy * 2 + kh;
        if (iy >= 64) continue;               // block-uniform
#pragma unroll
        for (int kw = 0; kw < 3; ++kw) {
            const int ix  = oxA * 2 + kw;
            const bool vld = (ix < 64);
            const size_t abase = (((size_t)bt * 64 + iy) * 64 + (vld ? ix : 0)) * 128 + lh * 8;
            const int tap = kh * 3 + kw;
#pragma unroll
            for (int ks = 0; ks < 4; ++ks) {
                bf16x8 a = *reinterpret_cast<const bf16x8*>(inS + abase + ks * 32);
                if (!vld) a = zero8();
                const short* wbase = wS + ((size_t)((tap * 4 + ks) * 16 + nh * 8) * 64 + l) * 8;
#pragma unroll
                for (int nt = 0; nt < 8; ++nt) {
                    bf16x8 bv = *reinterpret_cast<const bf16x8*>(wbase + nt * 512);
                    acc[nt] = __builtin_amdgcn_mfma_f32_16x16x32_bf16(a, bv, acc[nt], 0, 0, 0);
                }
            }
        }
    }

    const int oxC = mt * 16 + lh * 4;
    __hip_bfloat16* op = feat + (((size_t)bt * 32 + oy) * 32) * 256;
#pragma unroll
    for (int nt = 0; nt < 8; ++nt) {
        const int n = nh * 128 + nt * 16 + li;
        const float bias = b3[n];
#pragma unroll
        for (int r = 0; r < 4; ++r) {
            const float v = fmaxf(acc[nt][r] + bias, 0.f);
            op[(size_t)(oxC + r) * 256 + n] = __float2bfloat16(v);
        }
    }
}

// ---------- bilinear query sampling -> q bf16 [1024,256] ----------
__global__ __launch_bounds__(256) void k_sample(const float* __restrict__ qp,
                                                const __hip_bfloat16* __restrict__ feat,
                                                __hip_bfloat16* __restrict__ q)
{
    const int bn = blockIdx.x;
    const int b  = bn >> 9;
    const float t3 = qp[bn * 3 + 0];
    const float yv = qp[bn * 3 + 1] * 31.f;
    const float xv = qp[bn * 3 + 2] * 31.f;
    int t = (int)(t3 * 23.f);
    t = min(max(t, 0), 23);
    int y0 = (int)floorf(yv); y0 = min(max(y0, 0), 31);
    const int y1 = min(y0 + 1, 31);
    int x0 = (int)floorf(xv); x0 = min(max(x0, 0), 31);
    const int x1 = min(x0 + 1, 31);
    const float wy1 = yv - (float)y0, wy0 = 1.f - wy1;
    const float wx1 = xv - (float)x0, wx0 = 1.f - wx1;

    const int c = threadIdx.x;
    const __hip_bfloat16* fb = feat + ((size_t)(b * 24 + t) * 1024) * 256;
    const float f00 = __bfloat162float(fb[(size_t)(y0 * 32 + x0) * 256 + c]);
    const float f01 = __bfloat162float(fb[(size_t)(y0 * 32 + x1) * 256 + c]);
    const float f10 = __bfloat162float(fb[(size_t)(y1 * 32 + x0) * 256 + c]);
    const float f11 = __bfloat162float(fb[(size_t)(y1 * 32 + x1) * 256 + c]);
    const float v = (f00 * wx0 + f01 * wx1) * wy0 + (f10 * wx0 + f11 * wx1) * wy1;
    q[(size_t)bn * 256 + c] = __float2bfloat16(v);
}

// ---------- correlation MFMA + online softmax ----------
__global__ __launch_bounds__(256) void k_corrm(const __hip_bfloat16* __restrict__ qb,
                                               const __hip_bfloat16* __restrict__ featb,
                                               float* __restrict__ outp)
{
    const int blk = blockIdx.x;
    const int nc  = blk & 7;
    const int t   = (blk >> 3) % 24;
    const int bq  = blk / 192;
    const int w   = threadIdx.x >> 6;
    const int l   = threadIdx.x & 63;
    const int li  = l & 15, lh = l >> 4;

    const short* qS = (const short*)qb;
    const short* fS = (const short*)featb + (size_t)(bq * 24 + t) * 1024 * 256;

    const int qrowA = nc * 64 + w * 16 + li;
    bf16x8 aq[8];
#pragma unroll
    for (int ks = 0; ks < 8; ++ks)
        aq[ks] = *reinterpret_cast<const bf16x8*>(qS + ((size_t)(bq * 512 + qrowA)) * 256 + ks * 32 + lh * 8);

    float m[4], s[4], sx[4], sy[4], dmx[4];
#pragma unroll
    for (int r = 0; r < 4; ++r) { m[r] = -1e30f; s[r] = 0.f; sx[r] = 0.f; sy[r] = 0.f; dmx[r] = -1e30f; }

    for (int p0 = 0; p0 < 1024; p0 += 64) {
        f32x4 acc[4];
#pragma unroll
        for (int i = 0; i < 4; ++i) acc[i] = (f32x4){0.f, 0.f, 0.f, 0.f};

#pragma unroll
        for (int pt = 0; pt < 4; ++pt) {
            const short* bb = fS + (size_t)(p0 + pt * 16 + li) * 256 + lh * 8;
#pragma unroll
            for (int ks = 0; ks < 8; ++ks) {
                bf16x8 bv = *reinterpret_cast<const bf16x8*>(bb + ks * 32);
                acc[pt] = __builtin_amdgcn_mfma_f32_16x16x32_bf16(aq[ks], bv, acc[pt], 0, 0, 0);
            }
        }

        float px[4], py[4];
#pragma unroll
        for (int pt = 0; pt < 4; ++pt) {
            px[pt] = (float)((pt * 16 + li) & 31);
            py[pt] = (float)((p0 >> 5) + (pt >> 1));
        }

#pragma unroll
        for (int r = 0; r < 4; ++r) {
            const float v0 = acc[0][r], v1 = acc[1][r], v2 = acc[2][r], v3 = acc[3][r];
            float mx = fmaxf(fmaxf(v0, v1), fmaxf(v2, v3));
            mx = fmaxf(mx, __shfl_xor(mx, 1));
            mx = fmaxf(mx, __shfl_xor(mx, 2));
            mx = fmaxf(mx, __shfl_xor(mx, 4));
            mx = fmaxf(mx, __shfl_xor(mx, 8));
            dmx[r] = fmaxf(dmx[r], mx);
            const float mn = fmaxf(m[r], mx * 0.625f);
            const float sc = __expf(m[r] - mn);
            const float e0 = __expf(v0 * 0.625f - mn);
            const float e1 = __expf(v1 * 0.625f - mn);
            const float e2 = __expf(v2 * 0.625f - mn);
            const float e3 = __expf(v3 * 0.625f - mn);
            s[r]  = s[r]  * sc + (e0 + e1 + e2 + e3);
            sx[r] = sx[r] * sc + (e0 * px[0] + e1 * px[1] + e2 * px[2] + e3 * px[3]);
            sy[r] = sy[r] * sc + (e0 * py[0] + e1 * py[1] + e2 * py[2] + e3 * py[3]);
            m[r] = mn;
        }
    }

#pragma unroll
    for (int r = 0; r < 4; ++r) {
#pragma unroll
        for (int off = 1; off < 16; off <<= 1) {
            s[r]  += __shfl_xor(s[r],  off);
            sx[r] += __shfl_xor(sx[r], off);
            sy[r] += __shfl_xor(sy[r], off);
        }
    }

    if (li == 0) {
#pragma unroll
        for (int r = 0; r < 4; ++r) {
            const int n = nc * 64 + w * 16 + lh * 4 + r;
            const size_t idx = ((size_t)(bq * 512 + n)) * 24 + t;
            const float inv = 8.f / s[r];
            outp[idx * 2 + 0] = sx[r] * inv;
            outp[idx * 2 + 1] = sy[r] * inv;
            outp[49152 + idx] = 1.f / (1.f + __expf(dmx[r] * 0.0625f));
        }
    }
}

extern "C" void kernel_launch(void* const* d_in, const int* in_sizes, int n_in,
                              void* d_out, int out_size, void* d_ws, size_t ws_size,
                              hipStream_t stream)
{
    const float* video = (const float*)d_in[0];
    const float* qp    = (const float*)d_in[1];
    const float* w1    = (const float*)d_in[2];
    const float* b1    = (const float*)d_in[3];
    const float* w2    = (const float*)d_in[4];
    const float* b2    = (const float*)d_in[5];
    const float* w3    = (const float*)d_in[6];
    const float* b3    = (const float*)d_in[7];
    float* out = (float*)d_out;

    char* wsb = (char*)d_ws;
    __hip_bfloat16* c1o   = (__hip_bfloat16*)(wsb);                    // 100,663,296 B
    __hip_bfloat16* c2o   = (__hip_bfloat16*)(wsb + 100663296ull);     //  50,331,648 B
    // region at 150994944: pv (25,952,256 B, dead after k_conv1m) then featb (25,165,824 B)
    __hip_bfloat16* pv    = (__hip_bfloat16*)(wsb + 150994944ull);
    __hip_bfloat16* featb = (__hip_bfloat16*)(wsb + 150994944ull);
    __hip_bfloat16* qbuf  = (__hip_bfloat16*)(wsb + 176947200ull);     //     524,288 B
    __hip_bfloat16* w2p   = (__hip_bfloat16*)(wsb + 177471488ull);     //     147,456 B
    __hip_bfloat16* w3p   = (__hip_bfloat16*)(wsb + 177618944ull);     //     589,824 B
    __hip_bfloat16* w1p   = (__hip_bfloat16*)(wsb + 178208768ull);     //      28,672 B

    hipLaunchKernelGGL(k_repack1, dim3(56),       dim3(256), 0, stream, w1, w1p);
    hipLaunchKernelGGL(k_repack2, dim3(288),      dim3(256), 0, stream, w2, w2p);
    hipLaunchKernelGGL(k_repack3, dim3(1152),     dim3(256), 0, stream, w3, w3p);
    hipLaunchKernelGGL(k_pad1,    dim3(48 * 256), dim3(256), 0, stream, video, pv);
    hipLaunchKernelGGL(k_conv1m,  dim3(48 * 128), dim3(256), 0, stream, pv, w1p, b1, c1o);
    hipLaunchKernelGGL(k_conv2m,  dim3(48 * 64),  dim3(256), 0, stream, c1o, w2p, b2, c2o);
    hipLaunchKernelGGL(k_conv3m,  dim3(48 * 32),  dim3(256), 0, stream, c2o, w3p, b3, featb);
    hipLaunchKernelGGL(k_sample,  dim3(1024),     dim3(256), 0, stream, qp, featb, qbuf);
    hipLaunchKernelGGL(k_corrm,   dim3(384),      dim3(256), 0, stream, qbuf, featb, out);
}

// Round 4
// 378.879 us; speedup vs baseline: 11.3870x; 1.1589x over previous
//
#include <hip/hip_runtime.h>
#include <hip/hip_bf16.h>
#include <cstdint>
#include <cstddef>

// Pipeline (all convs MFMA, all conv inputs zero-padded so hot loops are branch-free):
//   k_pad1:   video[2,24,256,256,3]f32 -> pv[48,261,1056]bf16 (x-pad +-2 as 264px*4ch, y-pad rows 0,1,258,259,260)
//   k_conv1m: pv -> c1p[48,129,129,64]bf16 (interior [0,128)^2; pad strip zeroed)
//   k_conv2m: c1p -> c2p[48,65,65,128]bf16 (interior [0,64)^2; pad strip zeroed)
//   k_conv3m: c2p -> featb[48,32,32,256]bf16
//   k_sample: bilinear q[1024,256]bf16 ; k_corrm: MFMA corr + online softmax -> pred/occl f32
//
// MFMA 16x16x32 bf16 layouts (verified):
//   A: lane l holds row=l&15,   k=(l>>4)*8+j  (bf16x8 contiguous)
//   B: lane l holds col=l&15,   k=(l>>4)*8+j
//   C: lane l holds col=l&15, row=(l>>4)*4+reg (f32x4)

typedef __attribute__((ext_vector_type(8))) short bf16x8;
typedef __attribute__((ext_vector_type(4))) float f32x4;

__device__ __forceinline__ unsigned short bfr(float f) {
    return (unsigned short)(__bfloat16_as_ushort(__float2bfloat16(f)));
}

// ---------- pad+cast video: [48,256,256,3]f32 -> pv[48,261,1056]bf16 ----------
// row r holds input row iy=r-2; px p holds input ix=p-2 (4ch, ch3=0)
__global__ __launch_bounds__(256) void k_pad1(const float* __restrict__ video,
                                              __hip_bfloat16* __restrict__ pv)
{
    const int iy = blockIdx.x & 255;
    const int bt = blockIdx.x >> 8;
    const int ix = threadIdx.x;
    const float* src = video + ((size_t)(bt * 256 + iy) * 256 + ix) * 3;
    unsigned* dst = (unsigned*)(pv + ((size_t)(bt * 261) + iy + 2) * 1056);

    const float v0 = src[0], v1 = src[1], v2 = src[2];
    const unsigned lo = (unsigned)bfr(v0) | ((unsigned)bfr(v1) << 16);
    const unsigned hi = (unsigned)bfr(v2);
    dst[(2 + ix) * 2 + 0] = lo;
    dst[(2 + ix) * 2 + 1] = hi;
    if (ix < 2)   { dst[ix * 2] = 0u; dst[ix * 2 + 1] = 0u; }             // px 0,1
    if (ix >= 250){ dst[(ix + 8) * 2] = 0u; dst[(ix + 8) * 2 + 1] = 0u; } // px 258..263
}

// ---------- zero the pad strips of pv / c1p / c2p ----------
__global__ __launch_bounds__(256) void k_zeros(unsigned short* __restrict__ pv,
                                               unsigned short* __restrict__ c1p,
                                               unsigned short* __restrict__ c2p)
{
    const int i = blockIdx.x * 256 + threadIdx.x;     // 1,835,520 total (exact)
    if (i < 253440) {                                  // pv: 48 bt x 5 rows x 1056
        const int bt = i / 5280, rr = (i % 5280) / 1056, col = i % 1056;
        const int row = (rr < 2) ? rr : rr + 256;      // rows 0,1,258,259,260
        pv[(size_t)(bt * 261 + row) * 1056 + col] = 0;
    } else if (i < 1042944) {                          // c1p strips: 48 x 16448
        const int j = i - 253440, bt = j / 16448, k = j % 16448;
        size_t addr;
        if (k < 8256) { const int px = k >> 6, c = k & 63;                 // row 128
            addr = ((size_t)(bt * 129 + 128) * 129 + px) * 64 + c; }
        else { const int k2 = k - 8256, row = k2 >> 6, c = k2 & 63;        // col 128
            addr = ((size_t)(bt * 129 + row) * 129 + 128) * 64 + c; }
        c1p[addr] = 0;
    } else {                                           // c2p strips: 48 x 16512
        const int j = i - 1042944, bt = j / 16512, k = j % 16512;
        size_t addr;
        if (k < 8320) { const int px = k >> 7, c = k & 127;                // row 64
            addr = ((size_t)(bt * 65 + 64) * 65 + px) * 128 + c; }
        else { const int k2 = k - 8320, row = k2 >> 7, c = k2 & 127;       // col 64
            addr = ((size_t)(bt * 65 + row) * 65 + 64) * 128 + c; }
        c2p[addr] = 0;
    }
}

// ---------- all weight repacks (f32 -> bf16 B-fragment order), one kernel ----------
// wp1[kh(7)][nt(4)][lane][8]; wp2[tap(9)][ks(2)][nt(8)][lane][8]; wp3[tap(9)][ks(4)][nt(16)][lane][8]
__global__ __launch_bounds__(256) void k_repack_all(const float* __restrict__ w1,
                                                    const float* __restrict__ w2,
                                                    const float* __restrict__ w3,
                                                    __hip_bfloat16* __restrict__ wp1,
                                                    __hip_bfloat16* __restrict__ wp2,
                                                    __hip_bfloat16* __restrict__ wp3)
{
    const int e = blockIdx.x * 256 + threadIdx.x;     // 382,976 total (exact)
    if (e < 14336) {
        const int j = e & 7, lane = (e >> 3) & 63, nt = (e >> 9) & 3, kh = e >> 11;
        const int k = ((lane >> 4) << 3) + j;
        const int kw = k >> 2, ci = k & 3;
        const int n = nt * 16 + (lane & 15);
        float v = (ci < 3 && kw < 7) ? w1[(size_t)((kh * 7 + kw) * 3 + ci) * 64 + n] : 0.f;
        wp1[e] = __float2bfloat16(v);
    } else if (e < 88064) {
        const int e2 = e - 14336;
        const int j = e2 & 7, lane = (e2 >> 3) & 63, nt = (e2 >> 9) & 7, ks = (e2 >> 12) & 1, tap = e2 >> 13;
        const int ci = ks * 32 + ((lane >> 4) << 3) + j;
        const int n  = nt * 16 + (lane & 15);
        wp2[e2] = __float2bfloat16(w2[(size_t)(tap * 64 + ci) * 128 + n]);
    } else {
        const int e3 = e - 88064;
        const int j = e3 & 7, lane = (e3 >> 3) & 63, nt = (e3 >> 9) & 15, ks = (e3 >> 13) & 3, tap = e3 >> 15;
        const int ci = ks * 32 + ((lane >> 4) << 3) + j;
        const int n  = nt * 16 + (lane & 15);
        wp3[e3] = __float2bfloat16(w3[(size_t)(tap * 128 + ci) * 256 + n]);
    }
}

// ---------- conv1 MFMA: pv -> c1p[48,129,129,64] ----------
// block=(bt,oy) 6144 blocks x 4 waves; wave w: px [w*32, w*32+32), all 64 ch
__global__ __launch_bounds__(256) void k_conv1m(const __hip_bfloat16* __restrict__ pv,
                                                const __hip_bfloat16* __restrict__ wp,
                                                const float* __restrict__ b1,
                                                __hip_bfloat16* __restrict__ out)
{
    const int oy = blockIdx.x & 127;
    const int bt = blockIdx.x >> 7;
    const int w  = threadIdx.x >> 6;
    const int l  = threadIdx.x & 63;
    const int li = l & 15, lh = l >> 4;

    f32x4 acc[2][4];
#pragma unroll
    for (int m = 0; m < 2; ++m)
#pragma unroll
        for (int n = 0; n < 4; ++n) acc[m][n] = (f32x4){0.f, 0.f, 0.f, 0.f};

    const short* pvS = (const short*)pv;
    const short* wS  = (const short*)wp;

#pragma unroll
    for (int kh = 0; kh < 7; ++kh) {
        const short* row = pvS + (size_t)(bt * 261 + oy * 2 + kh) * 1056;   // padded rows, no branch
        bf16x8 bw[4];
#pragma unroll
        for (int nt = 0; nt < 4; ++nt)
            bw[nt] = *reinterpret_cast<const bf16x8*>(wS + ((size_t)(kh * 4 + nt) * 64 + l) * 8);
#pragma unroll
        for (int mt = 0; mt < 2; ++mt) {
            const int ox = w * 32 + mt * 16 + li;
            bf16x8 a = *reinterpret_cast<const bf16x8*>(row + 8 * (ox + lh));
#pragma unroll
            for (int nt = 0; nt < 4; ++nt)
                acc[mt][nt] = __builtin_amdgcn_mfma_f32_16x16x32_bf16(a, bw[nt], acc[mt][nt], 0, 0, 0);
        }
    }

    __hip_bfloat16* op = out + ((size_t)(bt * 129 + oy) * 129) * 64;
#pragma unroll
    for (int mt = 0; mt < 2; ++mt) {
        const int px0 = w * 32 + mt * 16 + lh * 4;
#pragma unroll
        for (int nt = 0; nt < 4; ++nt) {
            const int n = nt * 16 + li;
            const float bias = b1[n];
#pragma unroll
            for (int r = 0; r < 4; ++r) {
                const float v = fmaxf(acc[mt][nt][r] * (1.f / 255.f) + bias, 0.f);
                op[(size_t)(px0 + r) * 64 + n] = __float2bfloat16(v);
            }
        }
    }
}

// ---------- conv2 MFMA: c1p -> c2p[48,65,65,128] ----------
// grid (bt, oy2<32) = 1536 blocks x 512 thr (8 waves); wave w: row=w>>2, xq=w&3
// per wave: 16 px (ox=xq*16+li) x 128 ch; A hoisted per kh (6 frags); straight-line
__global__ __launch_bounds__(512, 4) void k_conv2m(const __hip_bfloat16* __restrict__ in,
                                                   const __hip_bfloat16* __restrict__ wp,
                                                   const float* __restrict__ b2,
                                                   __hip_bfloat16* __restrict__ out)
{
    const int oy2 = blockIdx.x & 31;
    const int bt  = blockIdx.x >> 5;
    const int w   = threadIdx.x >> 6;
    const int l   = threadIdx.x & 63;
    const int li  = l & 15, lh = l >> 4;
    const int row = w >> 2, xq = w & 3;
    const int oy  = oy2 * 2 + row;
    const int ox  = xq * 16 + li;

    f32x4 acc[8];
#pragma unroll
    for (int i = 0; i < 8; ++i) acc[i] = (f32x4){0.f, 0.f, 0.f, 0.f};

    const short* inS = (const short*)in;
    const short* wS  = (const short*)wp;
    const short* Abase = inS + ((size_t)(bt * 129 + oy * 2) * 129 + ox * 2) * 64 + lh * 8;
    const short* Bbase = wS + l * 8;

#pragma unroll
    for (int kh = 0; kh < 3; ++kh) {
        const short* Ak = Abase + kh * 8256;          // 129*64
        bf16x8 Af[3][2];
#pragma unroll
        for (int kw = 0; kw < 3; ++kw)
#pragma unroll
            for (int ks = 0; ks < 2; ++ks)
                Af[kw][ks] = *reinterpret_cast<const bf16x8*>(Ak + kw * 64 + ks * 32);
#pragma unroll
        for (int kw = 0; kw < 3; ++kw)
#pragma unroll
            for (int ks = 0; ks < 2; ++ks) {
                const short* wb = Bbase + (size_t)((kh * 3 + kw) * 2 + ks) * 4096;
#pragma unroll
                for (int nt = 0; nt < 8; ++nt) {
                    bf16x8 bv = *reinterpret_cast<const bf16x8*>(wb + nt * 512);
                    acc[nt] = __builtin_amdgcn_mfma_f32_16x16x32_bf16(Af[kw][ks], bv, acc[nt], 0, 0, 0);
                }
            }
    }

    __hip_bfloat16* op = out + ((size_t)(bt * 65 + oy) * 65) * 128;
#pragma unroll
    for (int nt = 0; nt < 8; ++nt) {
        const int n = nt * 16 + li;
        const float bias = b2[n];
#pragma unroll
        for (int r = 0; r < 4; ++r) {
            const int px = xq * 16 + lh * 4 + r;
            const float v = fmaxf(acc[nt][r] + bias, 0.f);
            op[(size_t)px * 128 + n] = __float2bfloat16(v);
        }
    }
}

// ---------- conv3 MFMA: c2p -> featb[48,32,32,256] ----------
// grid ((bt*16+oy2)*2+nh) = 1536 blocks x 512 thr; wave w: mq=w&3 (row=mq>>1, xh=mq&1), nh2=w>>2
// per wave: 16 px x 64 ch (nt0 = nh*8+nh2*4); A hoisted per kh (12 frags)
__global__ __launch_bounds__(512, 4) void k_conv3m(const __hip_bfloat16* __restrict__ in,
                                                   const __hip_bfloat16* __restrict__ wp,
                                                   const float* __restrict__ b3,
                                                   __hip_bfloat16* __restrict__ feat)
{
    const int blk = blockIdx.x;
    const int nh  = blk & 1;
    const int oy2 = (blk >> 1) & 15;
    const int bt  = blk >> 5;
    const int w   = threadIdx.x >> 6;
    const int l   = threadIdx.x & 63;
    const int li  = l & 15, lh = l >> 4;
    const int mq  = w & 3, nh2 = w >> 2;
    const int row = mq >> 1, xh = mq & 1;
    const int oy  = oy2 * 2 + row;
    const int ox  = xh * 16 + li;
    const int nt0 = nh * 8 + nh2 * 4;

    f32x4 acc[4];
#pragma unroll
    for (int i = 0; i < 4; ++i) acc[i] = (f32x4){0.f, 0.f, 0.f, 0.f};

    const short* inS = (const short*)in;
    const short* wS  = (const short*)wp;
    const short* Abase = inS + ((size_t)(bt * 65 + oy * 2) * 65 + ox * 2) * 128 + lh * 8;
    const short* Bbase = wS + (size_t)nt0 * 512 + l * 8;

#pragma unroll
    for (int kh = 0; kh < 3; ++kh) {
        const short* Ak = Abase + kh * 8320;          // 65*128
        bf16x8 Af[3][4];
#pragma unroll
        for (int kw = 0; kw < 3; ++kw)
#pragma unroll
            for (int ks = 0; ks < 4; ++ks)
                Af[kw][ks] = *reinterpret_cast<const bf16x8*>(Ak + kw * 128 + ks * 32);
#pragma unroll
        for (int kw = 0; kw < 3; ++kw)
#pragma unroll
            for (int ks = 0; ks < 4; ++ks) {
                const short* wb = Bbase + (size_t)((kh * 3 + kw) * 4 + ks) * 8192;
#pragma unroll
                for (int j = 0; j < 4; ++j) {
                    bf16x8 bv = *reinterpret_cast<const bf16x8*>(wb + j * 512);
                    acc[j] = __builtin_amdgcn_mfma_f32_16x16x32_bf16(Af[kw][ks], bv, acc[j], 0, 0, 0);
                }
            }
    }

    __hip_bfloat16* op = feat + ((size_t)(bt * 32 + oy) * 32) * 256;
#pragma unroll
    for (int j = 0; j < 4; ++j) {
        const int n = (nt0 + j) * 16 + li;
        const float bias = b3[n];
#pragma unroll
        for (int r = 0; r < 4; ++r) {
            const int px = xh * 16 + lh * 4 + r;
            const float v = fmaxf(acc[j][r] + bias, 0.f);
            op[(size_t)px * 256 + n] = __float2bfloat16(v);
        }
    }
}

// ---------- bilinear query sampling -> q bf16 [1024,256] ----------
__global__ __launch_bounds__(256) void k_sample(const float* __restrict__ qp,
                                                const __hip_bfloat16* __restrict__ feat,
                                                __hip_bfloat16* __restrict__ q)
{
    const int bn = blockIdx.x;
    const int b  = bn >> 9;
    const float t3 = qp[bn * 3 + 0];
    const float yv = qp[bn * 3 + 1] * 31.f;
    const float xv = qp[bn * 3 + 2] * 31.f;
    int t = (int)(t3 * 23.f);
    t = min(max(t, 0), 23);
    int y0 = (int)floorf(yv); y0 = min(max(y0, 0), 31);
    const int y1 = min(y0 + 1, 31);
    int x0 = (int)floorf(xv); x0 = min(max(x0, 0), 31);
    const int x1 = min(x0 + 1, 31);
    const float wy1 = yv - (float)y0, wy0 = 1.f - wy1;
    const float wx1 = xv - (float)x0, wx0 = 1.f - wx1;

    const int c = threadIdx.x;
    const __hip_bfloat16* fb = feat + ((size_t)(b * 24 + t) * 1024) * 256;
    const float f00 = __bfloat162float(fb[(size_t)(y0 * 32 + x0) * 256 + c]);
    const float f01 = __bfloat162float(fb[(size_t)(y0 * 32 + x1) * 256 + c]);
    const float f10 = __bfloat162float(fb[(size_t)(y1 * 32 + x0) * 256 + c]);
    const float f11 = __bfloat162float(fb[(size_t)(y1 * 32 + x1) * 256 + c]);
    const float v = (f00 * wx0 + f01 * wx1) * wy0 + (f10 * wx0 + f11 * wx1) * wy1;
    q[(size_t)bn * 256 + c] = __float2bfloat16(v);
}

// ---------- correlation MFMA + online softmax ----------
__global__ __launch_bounds__(256) void k_corrm(const __hip_bfloat16* __restrict__ qb,
                                               const __hip_bfloat16* __restrict__ featb,
                                               float* __restrict__ outp)
{
    const int blk = blockIdx.x;
    const int nc  = blk & 7;
    const int t   = (blk >> 3) % 24;
    const int bq  = blk / 192;
    const int w   = threadIdx.x >> 6;
    const int l   = threadIdx.x & 63;
    const int li  = l & 15, lh = l >> 4;

    const short* qS = (const short*)qb;
    const short* fS = (const short*)featb + (size_t)(bq * 24 + t) * 1024 * 256;

    const int qrowA = nc * 64 + w * 16 + li;
    bf16x8 aq[8];
#pragma unroll
    for (int ks = 0; ks < 8; ++ks)
        aq[ks] = *reinterpret_cast<const bf16x8*>(qS + ((size_t)(bq * 512 + qrowA)) * 256 + ks * 32 + lh * 8);

    float m[4], s[4], sx[4], sy[4], dmx[4];
#pragma unroll
    for (int r = 0; r < 4; ++r) { m[r] = -1e30f; s[r] = 0.f; sx[r] = 0.f; sy[r] = 0.f; dmx[r] = -1e30f; }

    for (int p0 = 0; p0 < 1024; p0 += 64) {
        f32x4 acc[4];
#pragma unroll
        for (int i = 0; i < 4; ++i) acc[i] = (f32x4){0.f, 0.f, 0.f, 0.f};

#pragma unroll
        for (int pt = 0; pt < 4; ++pt) {
            const short* bb = fS + (size_t)(p0 + pt * 16 + li) * 256 + lh * 8;
#pragma unroll
            for (int ks = 0; ks < 8; ++ks) {
                bf16x8 bv = *reinterpret_cast<const bf16x8*>(bb + ks * 32);
                acc[pt] = __builtin_amdgcn_mfma_f32_16x16x32_bf16(aq[ks], bv, acc[pt], 0, 0, 0);
            }
        }

        float px[4], py[4];
#pragma unroll
        for (int pt = 0; pt < 4; ++pt) {
            px[pt] = (float)((pt * 16 + li) & 31);
            py[pt] = (float)((p0 >> 5) + (pt >> 1));
        }

#pragma unroll
        for (int r = 0; r < 4; ++r) {
            const float v0 = acc[0][r], v1 = acc[1][r], v2 = acc[2][r], v3 = acc[3][r];
            float mx = fmaxf(fmaxf(v0, v1), fmaxf(v2, v3));
            mx = fmaxf(mx, __shfl_xor(mx, 1));
            mx = fmaxf(mx, __shfl_xor(mx, 2));
            mx = fmaxf(mx, __shfl_xor(mx, 4));
            mx = fmaxf(mx, __shfl_xor(mx, 8));
            dmx[r] = fmaxf(dmx[r], mx);
            const float mn = fmaxf(m[r], mx * 0.625f);
            const float sc = __expf(m[r] - mn);
            const float e0 = __expf(v0 * 0.625f - mn);
            const float e1 = __expf(v1 * 0.625f - mn);
            const float e2 = __expf(v2 * 0.625f - mn);
            const float e3 = __expf(v3 * 0.625f - mn);
            s[r]  = s[r]  * sc + (e0 + e1 + e2 + e3);
            sx[r] = sx[r] * sc + (e0 * px[0] + e1 * px[1] + e2 * px[2] + e3 * px[3]);
            sy[r] = sy[r] * sc + (e0 * py[0] + e1 * py[1] + e2 * py[2] + e3 * py[3]);
            m[r] = mn;
        }
    }

#pragma unroll
    for (int r = 0; r < 4; ++r) {
#pragma unroll
        for (int off = 1; off < 16; off <<= 1) {
            s[r]  += __shfl_xor(s[r],  off);
            sx[r] += __shfl_xor(sx[r], off);
            sy[r] += __shfl_xor(sy[r], off);
        }
    }

    if (li == 0) {
#pragma unroll
        for (int r = 0; r < 4; ++r) {
            const int n = nc * 64 + w * 16 + lh * 4 + r;
            const size_t idx = ((size_t)(bq * 512 + n)) * 24 + t;
            const float inv = 8.f / s[r];
            outp[idx * 2 + 0] = sx[r] * inv;
            outp[idx * 2 + 1] = sy[r] * inv;
            outp[49152 + idx] = 1.f / (1.f + __expf(dmx[r] * 0.0625f));
        }
    }
}

extern "C" void kernel_launch(void* const* d_in, const int* in_sizes, int n_in,
                              void* d_out, int out_size, void* d_ws, size_t ws_size,
                              hipStream_t stream)
{
    const float* video = (const float*)d_in[0];
    const float* qp    = (const float*)d_in[1];
    const float* w1    = (const float*)d_in[2];
    const float* b1    = (const float*)d_in[3];
    const float* w2    = (const float*)d_in[4];
    const float* b2    = (const float*)d_in[5];
    const float* w3    = (const float*)d_in[6];
    const float* b3    = (const float*)d_in[7];
    float* out = (float*)d_out;

    char* wsb = (char*)d_ws;
    __hip_bfloat16* c1p   = (__hip_bfloat16*)(wsb);                    // 102,242,304 B
    __hip_bfloat16* c2p   = (__hip_bfloat16*)(wsb + 102242304ull);     //  51,916,800 B
    // region at 154159104: pv (26,459,136 B, dead after conv1m) then featb (25,165,824 B)
    __hip_bfloat16* pv    = (__hip_bfloat16*)(wsb + 154159104ull);
    __hip_bfloat16* featb = (__hip_bfloat16*)(wsb + 154159104ull);
    __hip_bfloat16* qbuf  = (__hip_bfloat16*)(wsb + 180618240ull);     //     524,288 B
    __hip_bfloat16* w1p   = (__hip_bfloat16*)(wsb + 181142528ull);     //      28,672 B
    __hip_bfloat16* w2p   = (__hip_bfloat16*)(wsb + 181171200ull);     //     147,456 B
    __hip_bfloat16* w3p   = (__hip_bfloat16*)(wsb + 181318656ull);     //     589,824 B

    hipLaunchKernelGGL(k_repack_all, dim3(1496),     dim3(256), 0, stream, w1, w2, w3, w1p, w2p, w3p);
    hipLaunchKernelGGL(k_pad1,       dim3(48 * 256), dim3(256), 0, stream, video, pv);
    hipLaunchKernelGGL(k_zeros,      dim3(7170),     dim3(256), 0, stream,
                       (unsigned short*)pv, (unsigned short*)c1p, (unsigned short*)c2p);
    hipLaunchKernelGGL(k_conv1m,     dim3(48 * 128), dim3(256), 0, stream, pv, w1p, b1, c1p);
    hipLaunchKernelGGL(k_conv2m,     dim3(48 * 32),  dim3(512), 0, stream, c1p, w2p, b2, c2p);
    hipLaunchKernelGGL(k_conv3m,     dim3(48 * 32),  dim3(512), 0, stream, c2p, w3p, b3, featb);
    hipLaunchKernelGGL(k_sample,     dim3(1024),     dim3(256), 0, stream, qp, featb, qbuf);
    hipLaunchKernelGGL(k_corrm,      dim3(384),      dim3(256), 0, stream, qbuf, featb, out);
}

// Round 5
// 360.036 us; speedup vs baseline: 11.9830x; 1.0523x over previous
//
#include <hip/hip_runtime.h>
#include <hip/hip_bf16.h>
#include <cstdint>
#include <cstddef>

// Pipeline (all convs MFMA, all conv inputs zero-padded so hot loops are branch-free):
//   k_pad1:   video[2,24,256,256,3]f32 -> pv[48,261,1056]bf16
//   k_conv1m: pv -> c1p[48,129,129,64]bf16 ; k_conv2m: -> c2p[48,65,65,128]bf16
//   k_conv3m: -> featb[48,32,32,256]bf16
//   k_sample: bilinear q[1024,256]bf16
//   k_corrm:  MFMA corr + online softmax over 256-position chunks -> partials (m,s,sx,sy,dmax)
//   k_merge:  combine 4 position-chunk partials -> pred/occl f32
//
// MFMA 16x16x32 bf16 layouts (verified):
//   A: lane l holds row=l&15,   k=(l>>4)*8+j  (bf16x8 contiguous)
//   B: lane l holds col=l&15,   k=(l>>4)*8+j
//   C: lane l holds col=l&15, row=(l>>4)*4+reg (f32x4)

typedef __attribute__((ext_vector_type(8))) short bf16x8;
typedef __attribute__((ext_vector_type(4))) float f32x4;

__device__ __forceinline__ unsigned short bfr(float f) {
    return (unsigned short)(__bfloat16_as_ushort(__float2bfloat16(f)));
}

// ---------- pad+cast video: [48,256,256,3]f32 -> pv[48,261,1056]bf16 ----------
__global__ __launch_bounds__(256) void k_pad1(const float* __restrict__ video,
                                              __hip_bfloat16* __restrict__ pv)
{
    const int iy = blockIdx.x & 255;
    const int bt = blockIdx.x >> 8;
    const int ix = threadIdx.x;
    const float* src = video + ((size_t)(bt * 256 + iy) * 256 + ix) * 3;
    unsigned* dst = (unsigned*)(pv + ((size_t)(bt * 261) + iy + 2) * 1056);

    const float v0 = src[0], v1 = src[1], v2 = src[2];
    const unsigned lo = (unsigned)bfr(v0) | ((unsigned)bfr(v1) << 16);
    const unsigned hi = (unsigned)bfr(v2);
    dst[(2 + ix) * 2 + 0] = lo;
    dst[(2 + ix) * 2 + 1] = hi;
    if (ix < 2)   { dst[ix * 2] = 0u; dst[ix * 2 + 1] = 0u; }
    if (ix >= 250){ dst[(ix + 8) * 2] = 0u; dst[(ix + 8) * 2 + 1] = 0u; }
}

// ---------- zero the pad strips of pv / c1p / c2p ----------
__global__ __launch_bounds__(256) void k_zeros(unsigned short* __restrict__ pv,
                                               unsigned short* __restrict__ c1p,
                                               unsigned short* __restrict__ c2p)
{
    const int i = blockIdx.x * 256 + threadIdx.x;     // 1,835,520 total
    if (i < 253440) {
        const int bt = i / 5280, rr = (i % 5280) / 1056, col = i % 1056;
        const int row = (rr < 2) ? rr : rr + 256;
        pv[(size_t)(bt * 261 + row) * 1056 + col] = 0;
    } else if (i < 1042944) {
        const int j = i - 253440, bt = j / 16448, k = j % 16448;
        size_t addr;
        if (k < 8256) { const int px = k >> 6, c = k & 63;
            addr = ((size_t)(bt * 129 + 128) * 129 + px) * 64 + c; }
        else { const int k2 = k - 8256, row = k2 >> 6, c = k2 & 63;
            addr = ((size_t)(bt * 129 + row) * 129 + 128) * 64 + c; }
        c1p[addr] = 0;
    } else {
        const int j = i - 1042944, bt = j / 16512, k = j % 16512;
        size_t addr;
        if (k < 8320) { const int px = k >> 7, c = k & 127;
            addr = ((size_t)(bt * 65 + 64) * 65 + px) * 128 + c; }
        else { const int k2 = k - 8320, row = k2 >> 7, c = k2 & 127;
            addr = ((size_t)(bt * 65 + row) * 65 + 64) * 128 + c; }
        c2p[addr] = 0;
    }
}

// ---------- all weight repacks (f32 -> bf16 B-fragment order) ----------
__global__ __launch_bounds__(256) void k_repack_all(const float* __restrict__ w1,
                                                    const float* __restrict__ w2,
                                                    const float* __restrict__ w3,
                                                    __hip_bfloat16* __restrict__ wp1,
                                                    __hip_bfloat16* __restrict__ wp2,
                                                    __hip_bfloat16* __restrict__ wp3)
{
    const int e = blockIdx.x * 256 + threadIdx.x;     // 382,976 total
    if (e < 14336) {
        const int j = e & 7, lane = (e >> 3) & 63, nt = (e >> 9) & 3, kh = e >> 11;
        const int k = ((lane >> 4) << 3) + j;
        const int kw = k >> 2, ci = k & 3;
        const int n = nt * 16 + (lane & 15);
        float v = (ci < 3 && kw < 7) ? w1[(size_t)((kh * 7 + kw) * 3 + ci) * 64 + n] : 0.f;
        wp1[e] = __float2bfloat16(v);
    } else if (e < 88064) {
        const int e2 = e - 14336;
        const int j = e2 & 7, lane = (e2 >> 3) & 63, nt = (e2 >> 9) & 7, ks = (e2 >> 12) & 1, tap = e2 >> 13;
        const int ci = ks * 32 + ((lane >> 4) << 3) + j;
        const int n  = nt * 16 + (lane & 15);
        wp2[e2] = __float2bfloat16(w2[(size_t)(tap * 64 + ci) * 128 + n]);
    } else {
        const int e3 = e - 88064;
        const int j = e3 & 7, lane = (e3 >> 3) & 63, nt = (e3 >> 9) & 15, ks = (e3 >> 13) & 3, tap = e3 >> 15;
        const int ci = ks * 32 + ((lane >> 4) << 3) + j;
        const int n  = nt * 16 + (lane & 15);
        wp3[e3] = __float2bfloat16(w3[(size_t)(tap * 128 + ci) * 256 + n]);
    }
}

// ---------- conv1 MFMA: pv -> c1p[48,129,129,64] ----------
__global__ __launch_bounds__(256) void k_conv1m(const __hip_bfloat16* __restrict__ pv,
                                                const __hip_bfloat16* __restrict__ wp,
                                                const float* __restrict__ b1,
                                                __hip_bfloat16* __restrict__ out)
{
    const int oy = blockIdx.x & 127;
    const int bt = blockIdx.x >> 7;
    const int w  = threadIdx.x >> 6;
    const int l  = threadIdx.x & 63;
    const int li = l & 15, lh = l >> 4;

    f32x4 acc[2][4];
#pragma unroll
    for (int m = 0; m < 2; ++m)
#pragma unroll
        for (int n = 0; n < 4; ++n) acc[m][n] = (f32x4){0.f, 0.f, 0.f, 0.f};

    const short* pvS = (const short*)pv;
    const short* wS  = (const short*)wp;

#pragma unroll
    for (int kh = 0; kh < 7; ++kh) {
        const short* row = pvS + (size_t)(bt * 261 + oy * 2 + kh) * 1056;
        bf16x8 bw[4];
#pragma unroll
        for (int nt = 0; nt < 4; ++nt)
            bw[nt] = *reinterpret_cast<const bf16x8*>(wS + ((size_t)(kh * 4 + nt) * 64 + l) * 8);
#pragma unroll
        for (int mt = 0; mt < 2; ++mt) {
            const int ox = w * 32 + mt * 16 + li;
            bf16x8 a = *reinterpret_cast<const bf16x8*>(row + 8 * (ox + lh));
#pragma unroll
            for (int nt = 0; nt < 4; ++nt)
                acc[mt][nt] = __builtin_amdgcn_mfma_f32_16x16x32_bf16(a, bw[nt], acc[mt][nt], 0, 0, 0);
        }
    }

    __hip_bfloat16* op = out + ((size_t)(bt * 129 + oy) * 129) * 64;
#pragma unroll
    for (int mt = 0; mt < 2; ++mt) {
        const int px0 = w * 32 + mt * 16 + lh * 4;
#pragma unroll
        for (int nt = 0; nt < 4; ++nt) {
            const int n = nt * 16 + li;
            const float bias = b1[n];
#pragma unroll
            for (int r = 0; r < 4; ++r) {
                const float v = fmaxf(acc[mt][nt][r] * (1.f / 255.f) + bias, 0.f);
                op[(size_t)(px0 + r) * 64 + n] = __float2bfloat16(v);
            }
        }
    }
}

// ---------- conv2 MFMA: c1p -> c2p[48,65,65,128] ----------
__global__ __launch_bounds__(512, 4) void k_conv2m(const __hip_bfloat16* __restrict__ in,
                                                   const __hip_bfloat16* __restrict__ wp,
                                                   const float* __restrict__ b2,
                                                   __hip_bfloat16* __restrict__ out)
{
    const int oy2 = blockIdx.x & 31;
    const int bt  = blockIdx.x >> 5;
    const int w   = threadIdx.x >> 6;
    const int l   = threadIdx.x & 63;
    const int li  = l & 15, lh = l >> 4;
    const int row = w >> 2, xq = w & 3;
    const int oy  = oy2 * 2 + row;
    const int ox  = xq * 16 + li;

    f32x4 acc[8];
#pragma unroll
    for (int i = 0; i < 8; ++i) acc[i] = (f32x4){0.f, 0.f, 0.f, 0.f};

    const short* inS = (const short*)in;
    const short* wS  = (const short*)wp;
    const short* Abase = inS + ((size_t)(bt * 129 + oy * 2) * 129 + ox * 2) * 64 + lh * 8;
    const short* Bbase = wS + l * 8;

#pragma unroll
    for (int kh = 0; kh < 3; ++kh) {
        const short* Ak = Abase + kh * 8256;
        bf16x8 Af[3][2];
#pragma unroll
        for (int kw = 0; kw < 3; ++kw)
#pragma unroll
            for (int ks = 0; ks < 2; ++ks)
                Af[kw][ks] = *reinterpret_cast<const bf16x8*>(Ak + kw * 64 + ks * 32);
#pragma unroll
        for (int kw = 0; kw < 3; ++kw)
#pragma unroll
            for (int ks = 0; ks < 2; ++ks) {
                const short* wb = Bbase + (size_t)((kh * 3 + kw) * 2 + ks) * 4096;
#pragma unroll
                for (int nt = 0; nt < 8; ++nt) {
                    bf16x8 bv = *reinterpret_cast<const bf16x8*>(wb + nt * 512);
                    acc[nt] = __builtin_amdgcn_mfma_f32_16x16x32_bf16(Af[kw][ks], bv, acc[nt], 0, 0, 0);
                }
            }
    }

    __hip_bfloat16* op = out + ((size_t)(bt * 65 + oy) * 65) * 128;
#pragma unroll
    for (int nt = 0; nt < 8; ++nt) {
        const int n = nt * 16 + li;
        const float bias = b2[n];
#pragma unroll
        for (int r = 0; r < 4; ++r) {
            const int px = xq * 16 + lh * 4 + r;
            const float v = fmaxf(acc[nt][r] + bias, 0.f);
            op[(size_t)px * 128 + n] = __float2bfloat16(v);
        }
    }
}

// ---------- conv3 MFMA: c2p -> featb[48,32,32,256] ----------
__global__ __launch_bounds__(512, 4) void k_conv3m(const __hip_bfloat16* __restrict__ in,
                                                   const __hip_bfloat16* __restrict__ wp,
                                                   const float* __restrict__ b3,
                                                   __hip_bfloat16* __restrict__ feat)
{
    const int blk = blockIdx.x;
    const int nh  = blk & 1;
    const int oy2 = (blk >> 1) & 15;
    const int bt  = blk >> 5;
    const int w   = threadIdx.x >> 6;
    const int l   = threadIdx.x & 63;
    const int li  = l & 15, lh = l >> 4;
    const int mq  = w & 3, nh2 = w >> 2;
    const int row = mq >> 1, xh = mq & 1;
    const int oy  = oy2 * 2 + row;
    const int ox  = xh * 16 + li;
    const int nt0 = nh * 8 + nh2 * 4;

    f32x4 acc[4];
#pragma unroll
    for (int i = 0; i < 4; ++i) acc[i] = (f32x4){0.f, 0.f, 0.f, 0.f};

    const short* inS = (const short*)in;
    const short* wS  = (const short*)wp;
    const short* Abase = inS + ((size_t)(bt * 65 + oy * 2) * 65 + ox * 2) * 128 + lh * 8;
    const short* Bbase = wS + (size_t)nt0 * 512 + l * 8;

#pragma unroll
    for (int kh = 0; kh < 3; ++kh) {
        const short* Ak = Abase + kh * 8320;
        bf16x8 Af[3][4];
#pragma unroll
        for (int kw = 0; kw < 3; ++kw)
#pragma unroll
            for (int ks = 0; ks < 4; ++ks)
                Af[kw][ks] = *reinterpret_cast<const bf16x8*>(Ak + kw * 128 + ks * 32);
#pragma unroll
        for (int kw = 0; kw < 3; ++kw)
#pragma unroll
            for (int ks = 0; ks < 4; ++ks) {
                const short* wb = Bbase + (size_t)((kh * 3 + kw) * 4 + ks) * 8192;
#pragma unroll
                for (int j = 0; j < 4; ++j) {
                    bf16x8 bv = *reinterpret_cast<const bf16x8*>(wb + j * 512);
                    acc[j] = __builtin_amdgcn_mfma_f32_16x16x32_bf16(Af[kw][ks], bv, acc[j], 0, 0, 0);
                }
            }
    }

    __hip_bfloat16* op = feat + ((size_t)(bt * 32 + oy) * 32) * 256;
#pragma unroll
    for (int j = 0; j < 4; ++j) {
        const int n = (nt0 + j) * 16 + li;
        const float bias = b3[n];
#pragma unroll
        for (int r = 0; r < 4; ++r) {
            const int px = xh * 16 + lh * 4 + r;
            const float v = fmaxf(acc[j][r] + bias, 0.f);
            op[(size_t)px * 256 + n] = __float2bfloat16(v);
        }
    }
}

// ---------- bilinear query sampling -> q bf16 [1024,256] ----------
__global__ __launch_bounds__(256) void k_sample(const float* __restrict__ qp,
                                                const __hip_bfloat16* __restrict__ feat,
                                                __hip_bfloat16* __restrict__ q)
{
    const int bn = blockIdx.x;
    const int b  = bn >> 9;
    const float t3 = qp[bn * 3 + 0];
    const float yv = qp[bn * 3 + 1] * 31.f;
    const float xv = qp[bn * 3 + 2] * 31.f;
    int t = (int)(t3 * 23.f);
    t = min(max(t, 0), 23);
    int y0 = (int)floorf(yv); y0 = min(max(y0, 0), 31);
    const int y1 = min(y0 + 1, 31);
    int x0 = (int)floorf(xv); x0 = min(max(x0, 0), 31);
    const int x1 = min(x0 + 1, 31);
    const float wy1 = yv - (float)y0, wy0 = 1.f - wy1;
    const float wx1 = xv - (float)x0, wx0 = 1.f - wx1;

    const int c = threadIdx.x;
    const __hip_bfloat16* fb = feat + ((size_t)(b * 24 + t) * 1024) * 256;
    const float f00 = __bfloat162float(fb[(size_t)(y0 * 32 + x0) * 256 + c]);
    const float f01 = __bfloat162float(fb[(size_t)(y0 * 32 + x1) * 256 + c]);
    const float f10 = __bfloat162float(fb[(size_t)(y1 * 32 + x0) * 256 + c]);
    const float f11 = __bfloat162float(fb[(size_t)(y1 * 32 + x1) * 256 + c]);
    const float v = (f00 * wx0 + f01 * wx1) * wy0 + (f10 * wx0 + f11 * wx1) * wy1;
    q[(size_t)bn * 256 + c] = __float2bfloat16(v);
}

// ---------- correlation MFMA + online softmax over a 256-position chunk ----------
// grid 1536: bid -> xcd=bid&7 (6 images each, all 32 parts of an image on one XCD),
// part = (nc in 0..7, ps in 0..3). 4 waves x 16 queries; positions [ps*256,(ps+1)*256).
// partials (m,s,sx,sy,dmax) -> pbuf[5][4][24576]
__global__ __launch_bounds__(256) void k_corrm(const __hip_bfloat16* __restrict__ qb,
                                               const __hip_bfloat16* __restrict__ featb,
                                               float* __restrict__ pbuf)
{
    const int bid = blockIdx.x;
    const int xcd = bid & 7;
    const int sub = bid >> 3;          // 0..191
    const int grp = sub >> 5;          // 0..5
    const int prt = sub & 31;
    const int img = xcd * 6 + grp;     // 0..47
    const int bq  = img / 24, t = img % 24;
    const int nc  = prt & 7, ps = prt >> 3;

    const int w   = threadIdx.x >> 6;
    const int l   = threadIdx.x & 63;
    const int li  = l & 15, lh = l >> 4;

    const short* qS = (const short*)qb;
    const short* fS = (const short*)featb + (size_t)img * 1024 * 256;

    const int qrowA = nc * 64 + w * 16 + li;
    bf16x8 aq[8];
#pragma unroll
    for (int ks = 0; ks < 8; ++ks)
        aq[ks] = *reinterpret_cast<const bf16x8*>(qS + ((size_t)(bq * 512 + qrowA)) * 256 + ks * 32 + lh * 8);

    float m[4], s[4], sx[4], sy[4], dmx[4];
#pragma unroll
    for (int r = 0; r < 4; ++r) { m[r] = -1e30f; s[r] = 0.f; sx[r] = 0.f; sy[r] = 0.f; dmx[r] = -1e30f; }

    const int pbeg = ps * 256;
    for (int p0 = pbeg; p0 < pbeg + 256; p0 += 64) {
        f32x4 acc[4];
#pragma unroll
        for (int i = 0; i < 4; ++i) acc[i] = (f32x4){0.f, 0.f, 0.f, 0.f};

#pragma unroll
        for (int pt = 0; pt < 4; ++pt) {
            const short* bb = fS + (size_t)(p0 + pt * 16 + li) * 256 + lh * 8;
#pragma unroll
            for (int ks = 0; ks < 8; ++ks) {
                bf16x8 bv = *reinterpret_cast<const bf16x8*>(bb + ks * 32);
                acc[pt] = __builtin_amdgcn_mfma_f32_16x16x32_bf16(aq[ks], bv, acc[pt], 0, 0, 0);
            }
        }

        float px[4], py[4];
#pragma unroll
        for (int pt = 0; pt < 4; ++pt) {
            px[pt] = (float)((pt * 16 + li) & 31);
            py[pt] = (float)((p0 >> 5) + (pt >> 1));
        }

#pragma unroll
        for (int r = 0; r < 4; ++r) {
            const float v0 = acc[0][r], v1 = acc[1][r], v2 = acc[2][r], v3 = acc[3][r];
            float mx = fmaxf(fmaxf(v0, v1), fmaxf(v2, v3));
            mx = fmaxf(mx, __shfl_xor(mx, 1));
            mx = fmaxf(mx, __shfl_xor(mx, 2));
            mx = fmaxf(mx, __shfl_xor(mx, 4));
            mx = fmaxf(mx, __shfl_xor(mx, 8));
            dmx[r] = fmaxf(dmx[r], mx);
            const float mn = fmaxf(m[r], mx * 0.625f);
            const float sc = __expf(m[r] - mn);
            const float e0 = __expf(v0 * 0.625f - mn);
            const float e1 = __expf(v1 * 0.625f - mn);
            const float e2 = __expf(v2 * 0.625f - mn);
            const float e3 = __expf(v3 * 0.625f - mn);
            s[r]  = s[r]  * sc + (e0 + e1 + e2 + e3);
            sx[r] = sx[r] * sc + (e0 * px[0] + e1 * px[1] + e2 * px[2] + e3 * px[3]);
            sy[r] = sy[r] * sc + (e0 * py[0] + e1 * py[1] + e2 * py[2] + e3 * py[3]);
            m[r] = mn;
        }
    }

#pragma unroll
    for (int r = 0; r < 4; ++r) {
#pragma unroll
        for (int off = 1; off < 16; off <<= 1) {
            s[r]  += __shfl_xor(s[r],  off);
            sx[r] += __shfl_xor(sx[r], off);
            sy[r] += __shfl_xor(sy[r], off);
        }
    }

    if (li == 0) {
#pragma unroll
        for (int r = 0; r < 4; ++r) {
            const int n = nc * 64 + w * 16 + lh * 4 + r;
            const int bnt = (bq * 512 + n) * 24 + t;
            const int pi = ps * 24576 + bnt;
            pbuf[pi]               = m[r];
            pbuf[98304 + pi]       = s[r];
            pbuf[196608 + pi]      = sx[r];
            pbuf[294912 + pi]      = sy[r];
            pbuf[393216 + pi]      = dmx[r];
        }
    }
}

// ---------- merge 4 position-chunk partials -> outputs ----------
__global__ __launch_bounds__(256) void k_merge(const float* __restrict__ pbuf,
                                               float* __restrict__ outp)
{
    const int i = blockIdx.x * 256 + threadIdx.x;     // bnt in [0,24576)
    float M = -1e30f, D = -1e30f;
#pragma unroll
    for (int ps = 0; ps < 4; ++ps) {
        M = fmaxf(M, pbuf[ps * 24576 + i]);
        D = fmaxf(D, pbuf[393216 + ps * 24576 + i]);
    }
    float s = 0.f, sx = 0.f, sy = 0.f;
#pragma unroll
    for (int ps = 0; ps < 4; ++ps) {
        const int pi = ps * 24576 + i;
        const float wgt = __expf(pbuf[pi] - M);
        s  += pbuf[98304 + pi]  * wgt;
        sx += pbuf[196608 + pi] * wgt;
        sy += pbuf[294912 + pi] * wgt;
    }
    const float inv = 8.f / s;
    outp[i * 2 + 0] = sx * inv;
    outp[i * 2 + 1] = sy * inv;
    outp[49152 + i] = 1.f / (1.f + __expf(D * 0.0625f));
}

extern "C" void kernel_launch(void* const* d_in, const int* in_sizes, int n_in,
                              void* d_out, int out_size, void* d_ws, size_t ws_size,
                              hipStream_t stream)
{
    const float* video = (const float*)d_in[0];
    const float* qp    = (const float*)d_in[1];
    const float* w1    = (const float*)d_in[2];
    const float* b1    = (const float*)d_in[3];
    const float* w2    = (const float*)d_in[4];
    const float* b2    = (const float*)d_in[5];
    const float* w3    = (const float*)d_in[6];
    const float* b3    = (const float*)d_in[7];
    float* out = (float*)d_out;

    char* wsb = (char*)d_ws;
    __hip_bfloat16* c1p   = (__hip_bfloat16*)(wsb);                    // 102,242,304 B
    __hip_bfloat16* c2p   = (__hip_bfloat16*)(wsb + 102242304ull);     //  51,916,800 B
    __hip_bfloat16* pv    = (__hip_bfloat16*)(wsb + 154159104ull);     //  26,459,136 B (dead after conv1m)
    __hip_bfloat16* featb = (__hip_bfloat16*)(wsb + 154159104ull);     //  25,165,824 B
    __hip_bfloat16* qbuf  = (__hip_bfloat16*)(wsb + 180618240ull);     //     524,288 B
    __hip_bfloat16* w1p   = (__hip_bfloat16*)(wsb + 181142528ull);     //      28,672 B
    __hip_bfloat16* w2p   = (__hip_bfloat16*)(wsb + 181171200ull);     //     147,456 B
    __hip_bfloat16* w3p   = (__hip_bfloat16*)(wsb + 181318656ull);     //     589,824 B
    float*          pbuf  = (float*)(wsb + 181908480ull);              //   1,966,080 B

    hipLaunchKernelGGL(k_repack_all, dim3(1496),     dim3(256), 0, stream, w1, w2, w3, w1p, w2p, w3p);
    hipLaunchKernelGGL(k_pad1,       dim3(48 * 256), dim3(256), 0, stream, video, pv);
    hipLaunchKernelGGL(k_zeros,      dim3(7170),     dim3(256), 0, stream,
                       (unsigned short*)pv, (unsigned short*)c1p, (unsigned short*)c2p);
    hipLaunchKernelGGL(k_conv1m,     dim3(48 * 128), dim3(256), 0, stream, pv, w1p, b1, c1p);
    hipLaunchKernelGGL(k_conv2m,     dim3(48 * 32),  dim3(512), 0, stream, c1p, w2p, b2, c2p);
    hipLaunchKernelGGL(k_conv3m,     dim3(48 * 32),  dim3(512), 0, stream, c2p, w3p, b3, featb);
    hipLaunchKernelGGL(k_sample,     dim3(1024),     dim3(256), 0, stream, qp, featb, qbuf);
    hipLaunchKernelGGL(k_corrm,      dim3(1536),     dim3(256), 0, stream, qbuf, featb, pbuf);
    hipLaunchKernelGGL(k_merge,      dim3(96),       dim3(256), 0, stream, pbuf, out);
}

// Round 6
// 306.976 us; speedup vs baseline: 14.0542x; 1.1728x over previous
//
#include <hip/hip_runtime.h>
#include <hip/hip_bf16.h>
#include <cstdint>
#include <cstddef>

// Pipeline (all convs MFMA, all conv inputs zero-padded so hot loops are branch-free):
//   k_pad1:   video[2,24,256,256,3]f32 -> pv[48,261,1056]bf16
//   k_conv1m: pv -> c1p[48,129,129,64]bf16 ; k_conv2m: -> c2p[48,65,65,128]bf16
//   k_conv3m: -> featb[48,32,32,256]bf16
//   k_sample: bilinear q[1024,256]bf16
//   k_corrm:  LDS-staged MFMA corr + online softmax over 128-position chunks -> partials
//   k_merge:  combine 8 position-chunk partials -> pred/occl f32
//
// MFMA 16x16x32 bf16 layouts (verified):
//   A: lane l holds row=l&15,   k=(l>>4)*8+j  (bf16x8 contiguous)
//   B: lane l holds col=l&15,   k=(l>>4)*8+j
//   C: lane l holds col=l&15, row=(l>>4)*4+reg (f32x4)

typedef __attribute__((ext_vector_type(8))) short bf16x8;
typedef __attribute__((ext_vector_type(4))) float f32x4;

__device__ __forceinline__ unsigned short bfr(float f) {
    return (unsigned short)(__bfloat16_as_ushort(__float2bfloat16(f)));
}

// ---------- pad+cast video: [48,256,256,3]f32 -> pv[48,261,1056]bf16 ----------
__global__ __launch_bounds__(256) void k_pad1(const float* __restrict__ video,
                                              __hip_bfloat16* __restrict__ pv)
{
    const int iy = blockIdx.x & 255;
    const int bt = blockIdx.x >> 8;
    const int ix = threadIdx.x;
    const float* src = video + ((size_t)(bt * 256 + iy) * 256 + ix) * 3;
    unsigned* dst = (unsigned*)(pv + ((size_t)(bt * 261) + iy + 2) * 1056);

    const float v0 = src[0], v1 = src[1], v2 = src[2];
    const unsigned lo = (unsigned)bfr(v0) | ((unsigned)bfr(v1) << 16);
    const unsigned hi = (unsigned)bfr(v2);
    dst[(2 + ix) * 2 + 0] = lo;
    dst[(2 + ix) * 2 + 1] = hi;
    if (ix < 2)   { dst[ix * 2] = 0u; dst[ix * 2 + 1] = 0u; }
    if (ix >= 250){ dst[(ix + 8) * 2] = 0u; dst[(ix + 8) * 2 + 1] = 0u; }
}

// ---------- zero the pad strips of pv / c1p / c2p ----------
__global__ __launch_bounds__(256) void k_zeros(unsigned short* __restrict__ pv,
                                               unsigned short* __restrict__ c1p,
                                               unsigned short* __restrict__ c2p)
{
    const int i = blockIdx.x * 256 + threadIdx.x;     // 1,835,520 total
    if (i < 253440) {
        const int bt = i / 5280, rr = (i % 5280) / 1056, col = i % 1056;
        const int row = (rr < 2) ? rr : rr + 256;
        pv[(size_t)(bt * 261 + row) * 1056 + col] = 0;
    } else if (i < 1042944) {
        const int j = i - 253440, bt = j / 16448, k = j % 16448;
        size_t addr;
        if (k < 8256) { const int px = k >> 6, c = k & 63;
            addr = ((size_t)(bt * 129 + 128) * 129 + px) * 64 + c; }
        else { const int k2 = k - 8256, row = k2 >> 6, c = k2 & 63;
            addr = ((size_t)(bt * 129 + row) * 129 + 128) * 64 + c; }
        c1p[addr] = 0;
    } else {
        const int j = i - 1042944, bt = j / 16512, k = j % 16512;
        size_t addr;
        if (k < 8320) { const int px = k >> 7, c = k & 127;
            addr = ((size_t)(bt * 65 + 64) * 65 + px) * 128 + c; }
        else { const int k2 = k - 8320, row = k2 >> 7, c = k2 & 127;
            addr = ((size_t)(bt * 65 + row) * 65 + 64) * 128 + c; }
        c2p[addr] = 0;
    }
}

// ---------- all weight repacks (f32 -> bf16 B-fragment order) ----------
__global__ __launch_bounds__(256) void k_repack_all(const float* __restrict__ w1,
                                                    const float* __restrict__ w2,
                                                    const float* __restrict__ w3,
                                                    __hip_bfloat16* __restrict__ wp1,
                                                    __hip_bfloat16* __restrict__ wp2,
                                                    __hip_bfloat16* __restrict__ wp3)
{
    const int e = blockIdx.x * 256 + threadIdx.x;     // 382,976 total
    if (e < 14336) {
        const int j = e & 7, lane = (e >> 3) & 63, nt = (e >> 9) & 3, kh = e >> 11;
        const int k = ((lane >> 4) << 3) + j;
        const int kw = k >> 2, ci = k & 3;
        const int n = nt * 16 + (lane & 15);
        float v = (ci < 3 && kw < 7) ? w1[(size_t)((kh * 7 + kw) * 3 + ci) * 64 + n] : 0.f;
        wp1[e] = __float2bfloat16(v);
    } else if (e < 88064) {
        const int e2 = e - 14336;
        const int j = e2 & 7, lane = (e2 >> 3) & 63, nt = (e2 >> 9) & 7, ks = (e2 >> 12) & 1, tap = e2 >> 13;
        const int ci = ks * 32 + ((lane >> 4) << 3) + j;
        const int n  = nt * 16 + (lane & 15);
        wp2[e2] = __float2bfloat16(w2[(size_t)(tap * 64 + ci) * 128 + n]);
    } else {
        const int e3 = e - 88064;
        const int j = e3 & 7, lane = (e3 >> 3) & 63, nt = (e3 >> 9) & 15, ks = (e3 >> 13) & 3, tap = e3 >> 15;
        const int ci = ks * 32 + ((lane >> 4) << 3) + j;
        const int n  = nt * 16 + (lane & 15);
        wp3[e3] = __float2bfloat16(w3[(size_t)(tap * 128 + ci) * 256 + n]);
    }
}

// ---------- conv1 MFMA: pv -> c1p[48,129,129,64] ----------
__global__ __launch_bounds__(256) void k_conv1m(const __hip_bfloat16* __restrict__ pv,
                                                const __hip_bfloat16* __restrict__ wp,
                                                const float* __restrict__ b1,
                                                __hip_bfloat16* __restrict__ out)
{
    const int oy = blockIdx.x & 127;
    const int bt = blockIdx.x >> 7;
    const int w  = threadIdx.x >> 6;
    const int l  = threadIdx.x & 63;
    const int li = l & 15, lh = l >> 4;

    f32x4 acc[2][4];
#pragma unroll
    for (int m = 0; m < 2; ++m)
#pragma unroll
        for (int n = 0; n < 4; ++n) acc[m][n] = (f32x4){0.f, 0.f, 0.f, 0.f};

    const short* pvS = (const short*)pv;
    const short* wS  = (const short*)wp;

#pragma unroll
    for (int kh = 0; kh < 7; ++kh) {
        const short* row = pvS + (size_t)(bt * 261 + oy * 2 + kh) * 1056;
        bf16x8 bw[4];
#pragma unroll
        for (int nt = 0; nt < 4; ++nt)
            bw[nt] = *reinterpret_cast<const bf16x8*>(wS + ((size_t)(kh * 4 + nt) * 64 + l) * 8);
#pragma unroll
        for (int mt = 0; mt < 2; ++mt) {
            const int ox = w * 32 + mt * 16 + li;
            bf16x8 a = *reinterpret_cast<const bf16x8*>(row + 8 * (ox + lh));
#pragma unroll
            for (int nt = 0; nt < 4; ++nt)
                acc[mt][nt] = __builtin_amdgcn_mfma_f32_16x16x32_bf16(a, bw[nt], acc[mt][nt], 0, 0, 0);
        }
    }

    __hip_bfloat16* op = out + ((size_t)(bt * 129 + oy) * 129) * 64;
#pragma unroll
    for (int mt = 0; mt < 2; ++mt) {
        const int px0 = w * 32 + mt * 16 + lh * 4;
#pragma unroll
        for (int nt = 0; nt < 4; ++nt) {
            const int n = nt * 16 + li;
            const float bias = b1[n];
#pragma unroll
            for (int r = 0; r < 4; ++r) {
                const float v = fmaxf(acc[mt][nt][r] * (1.f / 255.f) + bias, 0.f);
                op[(size_t)(px0 + r) * 64 + n] = __float2bfloat16(v);
            }
        }
    }
}

// ---------- conv2 MFMA: c1p -> c2p[48,65,65,128] ----------
__global__ __launch_bounds__(512, 4) void k_conv2m(const __hip_bfloat16* __restrict__ in,
                                                   const __hip_bfloat16* __restrict__ wp,
                                                   const float* __restrict__ b2,
                                                   __hip_bfloat16* __restrict__ out)
{
    const int oy2 = blockIdx.x & 31;
    const int bt  = blockIdx.x >> 5;
    const int w   = threadIdx.x >> 6;
    const int l   = threadIdx.x & 63;
    const int li  = l & 15, lh = l >> 4;
    const int row = w >> 2, xq = w & 3;
    const int oy  = oy2 * 2 + row;
    const int ox  = xq * 16 + li;

    f32x4 acc[8];
#pragma unroll
    for (int i = 0; i < 8; ++i) acc[i] = (f32x4){0.f, 0.f, 0.f, 0.f};

    const short* inS = (const short*)in;
    const short* wS  = (const short*)wp;
    const short* Abase = inS + ((size_t)(bt * 129 + oy * 2) * 129 + ox * 2) * 64 + lh * 8;
    const short* Bbase = wS + l * 8;

#pragma unroll
    for (int kh = 0; kh < 3; ++kh) {
        const short* Ak = Abase + kh * 8256;
        bf16x8 Af[3][2];
#pragma unroll
        for (int kw = 0; kw < 3; ++kw)
#pragma unroll
            for (int ks = 0; ks < 2; ++ks)
                Af[kw][ks] = *reinterpret_cast<const bf16x8*>(Ak + kw * 64 + ks * 32);
#pragma unroll
        for (int kw = 0; kw < 3; ++kw)
#pragma unroll
            for (int ks = 0; ks < 2; ++ks) {
                const short* wb = Bbase + (size_t)((kh * 3 + kw) * 2 + ks) * 4096;
#pragma unroll
                for (int nt = 0; nt < 8; ++nt) {
                    bf16x8 bv = *reinterpret_cast<const bf16x8*>(wb + nt * 512);
                    acc[nt] = __builtin_amdgcn_mfma_f32_16x16x32_bf16(Af[kw][ks], bv, acc[nt], 0, 0, 0);
                }
            }
    }

    __hip_bfloat16* op = out + ((size_t)(bt * 65 + oy) * 65) * 128;
#pragma unroll
    for (int nt = 0; nt < 8; ++nt) {
        const int n = nt * 16 + li;
        const float bias = b2[n];
#pragma unroll
        for (int r = 0; r < 4; ++r) {
            const int px = xq * 16 + lh * 4 + r;
            const float v = fmaxf(acc[nt][r] + bias, 0.f);
            op[(size_t)px * 128 + n] = __float2bfloat16(v);
        }
    }
}

// ---------- conv3 MFMA: c2p -> featb[48,32,32,256] ----------
__global__ __launch_bounds__(512, 4) void k_conv3m(const __hip_bfloat16* __restrict__ in,
                                                   const __hip_bfloat16* __restrict__ wp,
                                                   const float* __restrict__ b3,
                                                   __hip_bfloat16* __restrict__ feat)
{
    const int blk = blockIdx.x;
    const int nh  = blk & 1;
    const int oy2 = (blk >> 1) & 15;
    const int bt  = blk >> 5;
    const int w   = threadIdx.x >> 6;
    const int l   = threadIdx.x & 63;
    const int li  = l & 15, lh = l >> 4;
    const int mq  = w & 3, nh2 = w >> 2;
    const int row = mq >> 1, xh = mq & 1;
    const int oy  = oy2 * 2 + row;
    const int ox  = xh * 16 + li;
    const int nt0 = nh * 8 + nh2 * 4;

    f32x4 acc[4];
#pragma unroll
    for (int i = 0; i < 4; ++i) acc[i] = (f32x4){0.f, 0.f, 0.f, 0.f};

    const short* inS = (const short*)in;
    const short* wS  = (const short*)wp;
    const short* Abase = inS + ((size_t)(bt * 65 + oy * 2) * 65 + ox * 2) * 128 + lh * 8;
    const short* Bbase = wS + (size_t)nt0 * 512 + l * 8;

#pragma unroll
    for (int kh = 0; kh < 3; ++kh) {
        const short* Ak = Abase + kh * 8320;
        bf16x8 Af[3][4];
#pragma unroll
        for (int kw = 0; kw < 3; ++kw)
#pragma unroll
            for (int ks = 0; ks < 4; ++ks)
                Af[kw][ks] = *reinterpret_cast<const bf16x8*>(Ak + kw * 128 + ks * 32);
#pragma unroll
        for (int kw = 0; kw < 3; ++kw)
#pragma unroll
            for (int ks = 0; ks < 4; ++ks) {
                const short* wb = Bbase + (size_t)((kh * 3 + kw) * 4 + ks) * 8192;
#pragma unroll
                for (int j = 0; j < 4; ++j) {
                    bf16x8 bv = *reinterpret_cast<const bf16x8*>(wb + j * 512);
                    acc[j] = __builtin_amdgcn_mfma_f32_16x16x32_bf16(Af[kw][ks], bv, acc[j], 0, 0, 0);
                }
            }
    }

    __hip_bfloat16* op = feat + ((size_t)(bt * 32 + oy) * 32) * 256;
#pragma unroll
    for (int j = 0; j < 4; ++j) {
        const int n = (nt0 + j) * 16 + li;
        const float bias = b3[n];
#pragma unroll
        for (int r = 0; r < 4; ++r) {
            const int px = xh * 16 + lh * 4 + r;
            const float v = fmaxf(acc[j][r] + bias, 0.f);
            op[(size_t)px * 256 + n] = __float2bfloat16(v);
        }
    }
}

// ---------- bilinear query sampling -> q bf16 [1024,256] ----------
__global__ __launch_bounds__(256) void k_sample(const float* __restrict__ qp,
                                                const __hip_bfloat16* __restrict__ feat,
                                                __hip_bfloat16* __restrict__ q)
{
    const int bn = blockIdx.x;
    const int b  = bn >> 9;
    const float t3 = qp[bn * 3 + 0];
    const float yv = qp[bn * 3 + 1] * 31.f;
    const float xv = qp[bn * 3 + 2] * 31.f;
    int t = (int)(t3 * 23.f);
    t = min(max(t, 0), 23);
    int y0 = (int)floorf(yv); y0 = min(max(y0, 0), 31);
    const int y1 = min(y0 + 1, 31);
    int x0 = (int)floorf(xv); x0 = min(max(x0, 0), 31);
    const int x1 = min(x0 + 1, 31);
    const float wy1 = yv - (float)y0, wy0 = 1.f - wy1;
    const float wx1 = xv - (float)x0, wx0 = 1.f - wx1;

    const int c = threadIdx.x;
    const __hip_bfloat16* fb = feat + ((size_t)(b * 24 + t) * 1024) * 256;
    const float f00 = __bfloat162float(fb[(size_t)(y0 * 32 + x0) * 256 + c]);
    const float f01 = __bfloat162float(fb[(size_t)(y0 * 32 + x1) * 256 + c]);
    const float f10 = __bfloat162float(fb[(size_t)(y1 * 32 + x0) * 256 + c]);
    const float f11 = __bfloat162float(fb[(size_t)(y1 * 32 + x1) * 256 + c]);
    const float v = (f00 * wx0 + f01 * wx1) * wy0 + (f10 * wx0 + f11 * wx1) * wy1;
    q[(size_t)bn * 256 + c] = __float2bfloat16(v);
}

// ---------- correlation: LDS-staged MFMA + online softmax (128 positions / block) ----------
// grid 1536: xcd=bid&7, 6 images/XCD; within image: nc in 0..3 (128 queries), ps in 0..7 (128 pos).
// 4 waves x 32 queries (2 mtiles). Position subtiles of 32 (= one feature row), double-buffered
// in LDS with XOR swizzle (write+read sides): LDS byte = pos*512 + (kb ^ ((pos&7)<<4)).
// partials (m,s,sx,sy,dmax) -> pbuf[5][8][24576]
__global__ __launch_bounds__(256, 2) void k_corrm(const __hip_bfloat16* __restrict__ qb,
                                                  const __hip_bfloat16* __restrict__ featb,
                                                  float* __restrict__ pbuf)
{
    __shared__ short lbuf[2][8192];          // 2 x 16KB

    const int bid = blockIdx.x;
    const int xcd = bid & 7;
    const int sub = bid >> 3;          // 0..191
    const int grp = sub >> 5;          // 0..5
    const int prt = sub & 31;
    const int img = xcd * 6 + grp;     // 0..47
    const int bq  = img / 24, t = img % 24;
    const int nc  = prt & 3, ps = prt >> 2;

    const int tid = threadIdx.x;
    const int w   = tid >> 6;
    const int l   = tid & 63;
    const int li  = l & 15, lh = l >> 4;

    const short* qS = (const short*)qb;
    const short* fS = (const short*)featb + (size_t)img * 1024 * 256;
    const char*  tile0 = (const char*)(fS + (size_t)(ps * 128) * 256);   // 128 pos x 512 B

    // A fragments: 32 queries (2 mtiles) x K=256
    const int q0 = nc * 128 + w * 32;
    bf16x8 aq[2][8];
#pragma unroll
    for (int mt = 0; mt < 2; ++mt)
#pragma unroll
        for (int ks = 0; ks < 8; ++ks)
            aq[mt][ks] = *reinterpret_cast<const bf16x8*>(
                qS + ((size_t)(bq * 512 + q0 + mt * 16 + li)) * 256 + ks * 32 + lh * 8);

    float m[2][4], s[2][4], sx[2][4], sy[2][4], dmx[2][4];
#pragma unroll
    for (int mt = 0; mt < 2; ++mt)
#pragma unroll
        for (int r = 0; r < 4; ++r) {
            m[mt][r] = -1e30f; s[mt][r] = 0.f; sx[mt][r] = 0.f; sy[mt][r] = 0.f; dmx[mt][r] = -1e30f;
        }

    // prologue: stage subtile 0 into buf 0 (thread stages granules g = i*256+tid)
    bf16x8 stg[4];
#pragma unroll
    for (int i = 0; i < 4; ++i) {
        const int g = i * 256 + tid;
        const int pos = g >> 5, kb = (g & 31) * 16;
        stg[i] = *reinterpret_cast<const bf16x8*>(tile0 + (size_t)pos * 512 + kb);
    }
#pragma unroll
    for (int i = 0; i < 4; ++i) {
        const int g = i * 256 + tid;
        const int pos = g >> 5, kb = (g & 31) * 16;
        *reinterpret_cast<bf16x8*>((char*)&lbuf[0][0] + pos * 512 + (kb ^ ((pos & 7) << 4))) = stg[i];
    }
    __syncthreads();

#pragma unroll
    for (int st = 0; st < 4; ++st) {
        const int cur = st & 1;

        // T14 async-split: issue next subtile's global loads before computing current
        if (st < 3) {
            const char* tn = tile0 + (size_t)((st + 1) * 32) * 512;
#pragma unroll
            for (int i = 0; i < 4; ++i) {
                const int g = i * 256 + tid;
                const int pos = g >> 5, kb = (g & 31) * 16;
                stg[i] = *reinterpret_cast<const bf16x8*>(tn + (size_t)pos * 512 + kb);
            }
        }

        // compute on lbuf[cur]: 16 ds_read_b128, 32 MFMA
        f32x4 acc[2][2];
#pragma unroll
        for (int mt = 0; mt < 2; ++mt)
#pragma unroll
            for (int pt = 0; pt < 2; ++pt) acc[mt][pt] = (f32x4){0.f, 0.f, 0.f, 0.f};

#pragma unroll
        for (int pt = 0; pt < 2; ++pt) {
            const int p = pt * 16 + li;
#pragma unroll
            for (int ks = 0; ks < 8; ++ks) {
                const int k = ks * 32 + lh * 8;
                bf16x8 bv = *reinterpret_cast<const bf16x8*>(&lbuf[cur][p * 256 + (k ^ ((p & 7) << 3))]);
                acc[0][pt] = __builtin_amdgcn_mfma_f32_16x16x32_bf16(aq[0][ks], bv, acc[0][pt], 0, 0, 0);
                acc[1][pt] = __builtin_amdgcn_mfma_f32_16x16x32_bf16(aq[1][ks], bv, acc[1][pt], 0, 0, 0);
            }
        }

        // online softmax update (this subtile = feature row py, columns 0..31)
        const float py = (float)(ps * 4 + st);
#pragma unroll
        for (int mt = 0; mt < 2; ++mt)
#pragma unroll
            for (int r = 0; r < 4; ++r) {
                const float v0 = acc[mt][0][r], v1 = acc[mt][1][r];   // px = li, li+16
                float mx = fmaxf(v0, v1);
                mx = fmaxf(mx, __shfl_xor(mx, 1));
                mx = fmaxf(mx, __shfl_xor(mx, 2));
                mx = fmaxf(mx, __shfl_xor(mx, 4));
                mx = fmaxf(mx, __shfl_xor(mx, 8));
                dmx[mt][r] = fmaxf(dmx[mt][r], mx);
                const float mn = fmaxf(m[mt][r], mx * 0.625f);        // logit = dot*(10/16)
                const float sc = __expf(m[mt][r] - mn);
                const float e0 = __expf(v0 * 0.625f - mn);
                const float e1 = __expf(v1 * 0.625f - mn);
                const float es = e0 + e1;
                s[mt][r]  = s[mt][r]  * sc + es;
                sx[mt][r] = sx[mt][r] * sc + es * (float)li + 16.f * e1;
                sy[mt][r] = sy[mt][r] * sc + es * py;
                m[mt][r] = mn;
            }

        // write next subtile into the other buffer, then one barrier
        if (st < 3) {
#pragma unroll
            for (int i = 0; i < 4; ++i) {
                const int g = i * 256 + tid;
                const int pos = g >> 5, kb = (g & 31) * 16;
                *reinterpret_cast<bf16x8*>((char*)&lbuf[cur ^ 1][0] + pos * 512 + (kb ^ ((pos & 7) << 4))) = stg[i];
            }
            __syncthreads();
        }
    }

    // reduce partial sums across the 16-lane group
#pragma unroll
    for (int mt = 0; mt < 2; ++mt)
#pragma unroll
        for (int r = 0; r < 4; ++r) {
#pragma unroll
            for (int off = 1; off < 16; off <<= 1) {
                s[mt][r]  += __shfl_xor(s[mt][r],  off);
                sx[mt][r] += __shfl_xor(sx[mt][r], off);
                sy[mt][r] += __shfl_xor(sy[mt][r], off);
            }
        }

    if (li == 0) {
#pragma unroll
        for (int mt = 0; mt < 2; ++mt)
#pragma unroll
            for (int r = 0; r < 4; ++r) {
                const int n = q0 + mt * 16 + lh * 4 + r;
                const int bnt = (bq * 512 + n) * 24 + t;
                const int pi = ps * 24576 + bnt;
                pbuf[pi]                = m[mt][r];
                pbuf[196608 + pi]       = s[mt][r];
                pbuf[393216 + pi]       = sx[mt][r];
                pbuf[589824 + pi]       = sy[mt][r];
                pbuf[786432 + pi]       = dmx[mt][r];
            }
    }
}

// ---------- merge 8 position-chunk partials -> outputs ----------
__global__ __launch_bounds__(256) void k_merge(const float* __restrict__ pbuf,
                                               float* __restrict__ outp)
{
    const int i = blockIdx.x * 256 + threadIdx.x;     // bnt in [0,24576)
    float M = -1e30f, D = -1e30f;
#pragma unroll
    for (int ps = 0; ps < 8; ++ps) {
        M = fmaxf(M, pbuf[ps * 24576 + i]);
        D = fmaxf(D, pbuf[786432 + ps * 24576 + i]);
    }
    float s = 0.f, sx = 0.f, sy = 0.f;
#pragma unroll
    for (int ps = 0; ps < 8; ++ps) {
        const int pi = ps * 24576 + i;
        const float wgt = __expf(pbuf[pi] - M);
        s  += pbuf[196608 + pi] * wgt;
        sx += pbuf[393216 + pi] * wgt;
        sy += pbuf[589824 + pi] * wgt;
    }
    const float inv = 8.f / s;
    outp[i * 2 + 0] = sx * inv;
    outp[i * 2 + 1] = sy * inv;
    outp[49152 + i] = 1.f / (1.f + __expf(D * 0.0625f));
}

extern "C" void kernel_launch(void* const* d_in, const int* in_sizes, int n_in,
                              void* d_out, int out_size, void* d_ws, size_t ws_size,
                              hipStream_t stream)
{
    const float* video = (const float*)d_in[0];
    const float* qp    = (const float*)d_in[1];
    const float* w1    = (const float*)d_in[2];
    const float* b1    = (const float*)d_in[3];
    const float* w2    = (const float*)d_in[4];
    const float* b2    = (const float*)d_in[5];
    const float* w3    = (const float*)d_in[6];
    const float* b3    = (const float*)d_in[7];
    float* out = (float*)d_out;

    char* wsb = (char*)d_ws;
    __hip_bfloat16* c1p   = (__hip_bfloat16*)(wsb);                    // 102,242,304 B
    __hip_bfloat16* c2p   = (__hip_bfloat16*)(wsb + 102242304ull);     //  51,916,800 B
    __hip_bfloat16* pv    = (__hip_bfloat16*)(wsb + 154159104ull);     //  26,459,136 B (dead after conv1m)
    __hip_bfloat16* featb = (__hip_bfloat16*)(wsb + 154159104ull);     //  25,165,824 B
    __hip_bfloat16* qbuf  = (__hip_bfloat16*)(wsb + 180618240ull);     //     524,288 B
    __hip_bfloat16* w1p   = (__hip_bfloat16*)(wsb + 181142528ull);     //      28,672 B
    __hip_bfloat16* w2p   = (__hip_bfloat16*)(wsb + 181171200ull);     //     147,456 B
    __hip_bfloat16* w3p   = (__hip_bfloat16*)(wsb + 181318656ull);     //     589,824 B
    float*          pbuf  = (float*)(wsb + 181908480ull);              //   3,932,160 B

    hipLaunchKernelGGL(k_repack_all, dim3(1496),     dim3(256), 0, stream, w1, w2, w3, w1p, w2p, w3p);
    hipLaunchKernelGGL(k_pad1,       dim3(48 * 256), dim3(256), 0, stream, video, pv);
    hipLaunchKernelGGL(k_zeros,      dim3(7170),     dim3(256), 0, stream,
                       (unsigned short*)pv, (unsigned short*)c1p, (unsigned short*)c2p);
    hipLaunchKernelGGL(k_conv1m,     dim3(48 * 128), dim3(256), 0, stream, pv, w1p, b1, c1p);
    hipLaunchKernelGGL(k_conv2m,     dim3(48 * 32),  dim3(512), 0, stream, c1p, w2p, b2, c2p);
    hipLaunchKernelGGL(k_conv3m,     dim3(48 * 32),  dim3(512), 0, stream, c2p, w3p, b3, featb);
    hipLaunchKernelGGL(k_sample,     dim3(1024),     dim3(256), 0, stream, qp, featb, qbuf);
    hipLaunchKernelGGL(k_corrm,      dim3(1536),     dim3(256), 0, stream, qbuf, featb, pbuf);
    hipLaunchKernelGGL(k_merge,      dim3(96),       dim3(256), 0, stream, pbuf, out);
}